// Round 2
// baseline (674.545 us; speedup 1.0000x reference)
//
#include <hip/hip_runtime.h>
#include <hip/hip_bf16.h>

// ---- types / helpers -------------------------------------------------------
typedef __attribute__((ext_vector_type(8))) short short8;
typedef __attribute__((ext_vector_type(4))) short short4v;
typedef __attribute__((ext_vector_type(4))) float float4v;
typedef __bf16 bf16x8 __attribute__((ext_vector_type(8)));

#define MFMA16(A,B,C) __builtin_amdgcn_mfma_f32_16x16x32_bf16( \
    __builtin_bit_cast(bf16x8,(A)), __builtin_bit_cast(bf16x8,(B)), (C), 0, 0, 0)

static __device__ __forceinline__ float bf2f(unsigned short b){
  unsigned u = ((unsigned)b) << 16; float f; __builtin_memcpy(&f,&u,sizeof(f)); return f;
}
static __device__ __forceinline__ unsigned short f2bf(float f){
  unsigned u; __builtin_memcpy(&u,&f,sizeof(u));
  u = (u + 0x7FFFu + ((u>>16)&1u)) >> 16; return (unsigned short)u;
}
static __device__ __forceinline__ float siluf(float x){
  return x * __builtin_amdgcn_rcpf(1.0f + __expf(-x));
}
static __device__ __forceinline__ float ldf(const float* p, size_t i){ return p[i]; }
static __device__ __forceinline__ float ldf(const unsigned short* p, size_t i){ return bf2f(p[i]); }

// ---- generic packed-B MFMA GEMM -------------------------------------------
// C[M x Nc] = op(A[M x K] @ W[K x Nc]); A row-major bf16; W pre-packed into
// 16x16x32 B-fragment tiles: Bp[(kt*NT + nt)*64 + lane][8].
// flags: 1=silu, 2=bias, 4=residual(res, stride ldoF)
__global__ __launch_bounds__(256) void k_gemm(
    const unsigned short* __restrict__ A, int lda,
    const unsigned short* __restrict__ Bp, int KT, int NT,
    const float* __restrict__ bias,
    float* __restrict__ outF, int ldoF,
    unsigned short* __restrict__ outH, int ldoH,
    const float* __restrict__ res,
    int Nc, int flags)
{
  const int w = threadIdx.x >> 6, lane = threadIdx.x & 63;
  const int l15 = lane & 15, q = lane >> 4;
  const int rowL = blockIdx.x * 64 + w * 16;   // wave's 16-row tile
  const int colB = blockIdx.y * 64;
  const short8* pa = (const short8*)(A + (size_t)(rowL + l15) * lda);
  const short8* pb = (const short8*)Bp;
  float4v acc[4] = {};
  int ntc[4];
  #pragma unroll
  for (int i = 0; i < 4; ++i){ int t = (colB >> 4) + i; ntc[i] = t < NT ? t : NT - 1; }
  for (int kt = 0; kt < KT; ++kt){
    short8 a = pa[kt * 4 + q];
    #pragma unroll
    for (int i = 0; i < 4; ++i){
      short8 b = pb[(size_t)(kt * NT + ntc[i]) * 64 + lane];
      acc[i] = MFMA16(a, b, acc[i]);
    }
  }
  const bool doB = flags & 2, doS = flags & 1, doR = flags & 4;
  #pragma unroll
  for (int i = 0; i < 4; ++i){
    int c = colB + i * 16 + l15;
    if (c >= Nc) continue;
    float bv = doB ? bias[c] : 0.0f;
    #pragma unroll
    for (int r = 0; r < 4; ++r){
      int row = rowL + q * 4 + r;
      float v = acc[i][r] + bv;
      if (doS) v = siluf(v);
      if (doR) v += res[(size_t)row * ldoF + c];
      if (outF) outF[(size_t)row * ldoF + c] = v;
      if (outH) outH[(size_t)row * ldoH + c] = f2bf(v);
    }
  }
}

// ---- weight packing into fragment order ------------------------------------
// dst tile index (kt*NTtot + ntoff + nt); value = W[kt*32 + q*8 + j][nt*16 + l15]
template<typename T>
static __device__ __forceinline__ void pack_tile(
    const T* W, int ldw, int Krows, int Ncols,
    unsigned short* dst, int NTtot, int ntoff, int kt, int nt,
    const float* addrow)
{
  int lane = threadIdx.x;
  int l15 = lane & 15, q = lane >> 4;
  int col = nt * 16 + l15;
  int kr0 = kt * 32 + q * 8;
  short8 v;
  #pragma unroll
  for (int j = 0; j < 8; ++j){
    int r = kr0 + j;
    float x = 0.0f;
    if (r < Krows && col < Ncols){
      x = ldf(W, (size_t)r * ldw + col);
      if (addrow) x += addrow[(r >> 5) * 256 + col];
    }
    v[j] = (short)f2bf(x);
  }
  ((short8*)dst)[(size_t)(kt * NTtot + ntoff + nt) * 64 + lane] = v;
}

__global__ void k_pack_misc(
    const float* Ws, const float* Wn,
    const float* typeW, const float* polarW, const float* fracW,
    unsigned short* Wsp, unsigned short* Wnp, unsigned short* typep,
    unsigned short* polarp, unsigned short* fracp)
{
  int b = blockIdx.x;
  if (b < 64)        pack_tile(Ws,    256, 100, 256, Wsp,   16, 0, b >> 4, b & 15, nullptr);
  else if (b < 256){ int s = b - 64;  pack_tile(Wn,    256, 384, 256, Wnp,   16, 0, s >> 4, s & 15, nullptr); }
  else if (b < 312){ int s = b - 256; pack_tile(typeW, 100, 256, 100, typep,  7, 0, s / 7,  s % 7,  nullptr); }
  else if (b < 320){ int s = b - 312; pack_tile(polarW,  6, 256,   6, polarp, 1, 0, s, 0, nullptr); }
  else             { int s = b - 320; pack_tile(fracW,   3, 256,   3, fracp,  1, 0, s, 0, nullptr); }
}

__global__ void k_pack_layer(
    const float* m1Wl, const float* m2Wl,
    const float* a1Wl, const float* a2Wl,
    unsigned short* W12p, unsigned short* W1botp, unsigned short* W2Tp,
    unsigned short* a1p, unsigned short* a2p)
{
  int b = blockIdx.x;
  if (b < 128)       pack_tile(m1Wl,           256, 256, 256, W12p,  32,  0, b >> 4, b & 15, nullptr);
  else if (b < 256){ int s = b - 128; pack_tile(m1Wl + 256*256, 256, 256, 256, W12p,  32, 16, s >> 4, s & 15, nullptr); }
  else if (b < 288){ int s = b - 256; pack_tile(m1Wl + 512*256, 256,  64, 256, W1botp,16,  0, s >> 4, s & 15, nullptr); }
  else if (b < 416){ int s = b - 288; pack_tile(m2Wl,           256, 256, 256, W2Tp,  16,  0, s >> 4, s & 15, nullptr); }
  else if (b < 672){ int s = b - 416; pack_tile(a1Wl,           256, 512, 256, a1p,   16,  0, s >> 4, s & 15, nullptr); }
  else             { int s = b - 672; pack_tile(a2Wl,           256, 256, 256, a2p,   16,  0, s >> 4, s & 15, nullptr); }
}

// pack P2^T (per graph, kt==graph) and P1^T (+lpw per graph) from P12[4096x512]
__global__ void k_pack_P(const unsigned short* P12, const float* lpwl,
                         unsigned short* P1Tp, unsigned short* P2Tp)
{
  int b = blockIdx.x;
  if (b < 2048)      pack_tile(P12 + 256, 512, 4096, 256, P2Tp, 16, 0, b >> 4, b & 15, nullptr);
  else { int s = b - 2048; pack_tile(P12, 512, 4096, 256, P1Tp, 16, 0, s >> 4, s & 15, lpwl); }
}

// ---- small prep kernels ----------------------------------------------------
__global__ void k_pad(const float* at, unsigned short* atp)
{
  int id = blockIdx.x * 256 + threadIdx.x;   // 4096*128
  int r = id >> 7, c = id & 127;
  atp[id] = (c < 100) ? f2bf(at[r * 100 + c]) : (unsigned short)0;
}

__global__ void k_time(const float* t, unsigned short* cat1)
{
  int g = blockIdx.x, i = threadIdx.x;       // 128 x 128
  float tg = t[g];
  int f = i & 63;
  float fr = __expf((-9.210340371976184f / 63.0f) * (float)f);
  float arg = tg * fr;
  float v = (i < 64) ? __sinf(arg) : __cosf(arg);
  unsigned short hv = f2bf(v);
  for (int n = 0; n < 32; ++n)
    cat1[(size_t)(g * 32 + n) * 384 + 256 + i] = hv;
}

__global__ void k_femb(const float* fc, unsigned short* femb)
{
  int e = blockIdx.x * 256 + threadIdx.x;    // E = 131072
  int g = e >> 10, i = (e >> 5) & 31, j = e & 31;
  int nt = g * 32 + i, ns = g * 32 + j;
  unsigned short o[64];
  #pragma unroll
  for (int k = 0; k < 3; ++k){
    float d = fc[ns * 3 + k] - fc[nt * 3 + k];
    d -= floorf(d);
    #pragma unroll
    for (int f = 0; f < 10; ++f){
      float ang = d * (6.283185307179586f * (float)f);
      o[k * 10 + f]      = f2bf(__sinf(ang));
      o[30 + k * 10 + f] = f2bf(__cosf(ang));
    }
  }
  #pragma unroll
  for (int z = 60; z < 64; ++z) o[z] = 0;
  short8* dst = (short8*)(femb + (size_t)e * 64);
  #pragma unroll
  for (int v = 0; v < 8; ++v){
    short8 s;
    #pragma unroll
    for (int j2 = 0; j2 < 8; ++j2) s[j2] = (short)o[v * 8 + j2];
    dst[v] = s;
  }
}

// lpw[l][g][c] = m1_b[l][c] + sum_k l_polar[g,k]*m1_W[l][572+k][c]
__global__ void k_lpw(const float* lpol, const float* m1W,
                      const float* m1b, float* lpw)
{
  int l = blockIdx.x >> 7, g = blockIdx.x & 127, c = threadIdx.x;
  const float* W = m1W + (size_t)l * 578 * 256;
  float acc = m1b[l * 256 + c];
  #pragma unroll
  for (int k = 0; k < 6; ++k)
    acc += lpol[g * 6 + k] * W[(572 + k) * 256 + c];
  lpw[((size_t)l * 128 + g) * 256 + c] = acc;
}

// layernorm: 4 rows/block (1 wave each), H=256
__global__ __launch_bounds__(256) void k_ln(
    const float* __restrict__ nf, const float* __restrict__ g,
    const float* __restrict__ bta, unsigned short* __restrict__ h)
{
  int w = threadIdx.x >> 6, lane = threadIdx.x & 63;
  int row = blockIdx.x * 4 + w;
  float4v x = *(const float4v*)(nf + (size_t)row * 256 + lane * 4);
  float s = x[0] + x[1] + x[2] + x[3];
  #pragma unroll
  for (int m = 1; m < 64; m <<= 1) s += __shfl_xor(s, m, 64);
  float mu = s * (1.0f / 256.0f);
  float d0 = x[0] - mu, d1 = x[1] - mu, d2 = x[2] - mu, d3 = x[3] - mu;
  float vs = d0 * d0 + d1 * d1 + d2 * d2 + d3 * d3;
  #pragma unroll
  for (int m = 1; m < 64; m <<= 1) vs += __shfl_xor(vs, m, 64);
  float rs = rsqrtf(vs * (1.0f / 256.0f) + 1e-5f);
  float4v gg = *(const float4v*)(g + lane * 4);
  float4v bb = *(const float4v*)(bta + lane * 4);
  short4v o;
  o[0] = (short)f2bf(d0 * rs * gg[0] + bb[0]);
  o[1] = (short)f2bf(d1 * rs * gg[1] + bb[1]);
  o[2] = (short)f2bf(d2 * rs * gg[2] + bb[2]);
  o[3] = (short)f2bf(d3 * rs * gg[3] + bb[3]);
  *(short4v*)(h + (size_t)row * 256 + lane * 4) = o;
}

__global__ void k_gmean(const unsigned short* h, unsigned short* gf)
{
  int g = blockIdx.x, c = threadIdx.x;
  float s = 0.0f;
  for (int n = 0; n < 32; ++n) s += bf2f(h[(size_t)(g * 32 + n) * 256 + c]);
  gf[g * 256 + c] = f2bf(s * (1.0f / 32.0f));
}

// ---- fused edge kernel -----------------------------------------------------
// block = 8 waves = 512 thr, covers 256 edges (8 target nodes) in 2 halves.
// M1^T = MFMA over K=128: [femb(64) | src-onehot(32)->P2 | node-onehot(32)->P1+lpw]
// then M2^T = M1 @ m2_W via W2^T frags, silu, mean over 32 edges -> cat2 right half.
#define EST 264
__global__ __launch_bounds__(512, 4) void k_edge(
    const unsigned short* __restrict__ femb,
    const unsigned short* __restrict__ W1botp,
    const unsigned short* __restrict__ P1Tp,
    const unsigned short* __restrict__ P2Tp,
    const unsigned short* __restrict__ W2Tp,
    const float* __restrict__ b2,
    unsigned short* __restrict__ cat2)
{
  __shared__ unsigned short M1[128 * EST];   // 67.6 KB
  const int w = threadIdx.x >> 6, lane = threadIdx.x & 63;
  const int l15 = lane & 15, q = lane >> 4;
  const int b = blockIdx.x, g = b >> 2;
  const int cb = w * 32;                     // wave's 32-channel chunk
  const short8* fb8  = (const short8*)femb;
  const short8* w1b8 = (const short8*)W1botp;
  const short8* p1t8 = (const short8*)P1Tp;
  const short8* p2t8 = (const short8*)P2Tp;
  const short8* w2t8 = (const short8*)W2Tp;

  short8 ohj[2];                             // src-onehot per e-tile parity
  #pragma unroll
  for (int p = 0; p < 2; ++p){
    int tgt = p * 16 + l15;
    #pragma unroll
    for (int j = 0; j < 8; ++j) ohj[p][j] = (short)((q * 8 + j) == tgt ? 0x3F80 : 0);
  }

  for (int half = 0; half < 2; ++half){
    short8 ohn[4];                           // node-onehot per node in half
    #pragma unroll
    for (int nn = 0; nn < 4; ++nn){
      int tgt = (b & 3) * 8 + half * 4 + nn;
      #pragma unroll
      for (int j = 0; j < 8; ++j) ohn[nn][j] = (short)((q * 8 + j) == tgt ? 0x3F80 : 0);
    }
    // ---- build M1^T ----
    float4v acc[2][8] = {};
    #pragma unroll
    for (int ks = 0; ks < 4; ++ks){
      short8 a0, a1;
      if (ks < 2)      { a0 = w1b8[(size_t)(ks * 16 + w * 2 + 0) * 64 + lane];
                         a1 = w1b8[(size_t)(ks * 16 + w * 2 + 1) * 64 + lane]; }
      else if (ks == 2){ a0 = p2t8[(size_t)(g * 16 + w * 2 + 0) * 64 + lane];
                         a1 = p2t8[(size_t)(g * 16 + w * 2 + 1) * 64 + lane]; }
      else             { a0 = p1t8[(size_t)(g * 16 + w * 2 + 0) * 64 + lane];
                         a1 = p1t8[(size_t)(g * 16 + w * 2 + 1) * 64 + lane]; }
      #pragma unroll
      for (int et = 0; et < 8; ++et){
        short8 bf;
        if (ks < 2){
          int edge = b * 256 + half * 128 + et * 16 + l15;
          bf = fb8[(size_t)edge * 8 + ks * 4 + q];
        } else if (ks == 2) bf = ohj[et & 1];
        else                bf = ohn[et >> 1];
        acc[0][et] = MFMA16(a0, bf, acc[0][et]);
        acc[1][et] = MFMA16(a1, bf, acc[1][et]);
      }
    }
    // silu -> M1 LDS (row e, contiguous channels)
    #pragma unroll
    for (int ct = 0; ct < 2; ++ct)
      #pragma unroll
      for (int et = 0; et < 8; ++et){
        short4v sv;
        #pragma unroll
        for (int r = 0; r < 4; ++r) sv[r] = (short)f2bf(siluf(acc[ct][et][r]));
        *(short4v*)(&M1[(size_t)(et * 16 + l15) * EST + cb + ct * 16 + q * 4]) = sv;
      }
    __syncthreads();
    // ---- M2^T ----
    float4v c2[2][8] = {};
    #pragma unroll
    for (int kt = 0; kt < 8; ++kt){
      short8 a0 = w2t8[(size_t)(kt * 16 + w * 2 + 0) * 64 + lane];
      short8 a1 = w2t8[(size_t)(kt * 16 + w * 2 + 1) * 64 + lane];
      #pragma unroll
      for (int et = 0; et < 8; ++et){
        short8 bf = *(const short8*)(&M1[(size_t)(et * 16 + l15) * EST + kt * 32 + q * 8]);
        c2[0][et] = MFMA16(a0, bf, c2[0][et]);
        c2[1][et] = MFMA16(a1, bf, c2[1][et]);
      }
    }
    __syncthreads();
    // bias + silu + mean over 32 edges -> cat2[node][256 + c]
    float bv[2][4];
    #pragma unroll
    for (int ct = 0; ct < 2; ++ct)
      #pragma unroll
      for (int r = 0; r < 4; ++r) bv[ct][r] = b2[cb + ct * 16 + q * 4 + r];
    #pragma unroll
    for (int nn = 0; nn < 4; ++nn){
      float vv[2][4];
      #pragma unroll
      for (int ct = 0; ct < 2; ++ct)
        #pragma unroll
        for (int r = 0; r < 4; ++r){
          float v = siluf(c2[ct][2 * nn][r] + bv[ct][r])
                  + siluf(c2[ct][2 * nn + 1][r] + bv[ct][r]);
          v += __shfl_xor(v, 1, 16);
          v += __shfl_xor(v, 2, 16);
          v += __shfl_xor(v, 4, 16);
          v += __shfl_xor(v, 8, 16);
          vv[ct][r] = v;
        }
      if (l15 == 0){
        int node = b * 8 + half * 4 + nn;
        #pragma unroll
        for (int ct = 0; ct < 2; ++ct)
          #pragma unroll
          for (int r = 0; r < 4; ++r)
            cat2[(size_t)node * 512 + 256 + cb + ct * 16 + q * 4 + r] =
                f2bf(vv[ct][r] * (1.0f / 32.0f));
      }
    }
  }
}

// ---- launcher --------------------------------------------------------------
extern "C" void kernel_launch(void* const* d_in, const int* in_sizes, int n_in,
                              void* d_out, int out_size, void* d_ws, size_t ws_size,
                              hipStream_t stream)
{
  const float* t      = (const float*)d_in[0];
  const float* at     = (const float*)d_in[1];
  const float* fc     = (const float*)d_in[2];
  const float* lpol   = (const float*)d_in[3];
  const float* Ws     = (const float*)d_in[5];
  const float* bs     = (const float*)d_in[6];
  const float* Wn     = (const float*)d_in[7];
  const float* bn     = (const float*)d_in[8];
  const float* ln_g   = (const float*)d_in[9];
  const float* ln_b   = (const float*)d_in[10];
  const float* m1W    = (const float*)d_in[11];
  const float* m1b    = (const float*)d_in[12];
  const float* m2W    = (const float*)d_in[13];
  const float* m2b    = (const float*)d_in[14];
  const float* a1W    = (const float*)d_in[15];
  const float* a1b    = (const float*)d_in[16];
  const float* a2W    = (const float*)d_in[17];
  const float* a2b    = (const float*)d_in[18];
  const float* flng   = (const float*)d_in[19];
  const float* flnb   = (const float*)d_in[20];
  const float* typeW  = (const float*)d_in[21];
  const float* typeb  = (const float*)d_in[22];
  const float* polarW = (const float*)d_in[23];
  const float* fracW  = (const float*)d_in[24];
  float* out = (float*)d_out;

  char* ws = (char*)d_ws;
  size_t off = 0;
  auto alloc = [&](size_t bytes) -> char* {
    char* p = ws + off; off += (bytes + 255) & ~(size_t)255; return p;
  };
  float*          nf    = (float*)         alloc((size_t)4096*256*4);
  unsigned short* cat2  = (unsigned short*)alloc((size_t)4096*512*2);
  unsigned short* h     = (unsigned short*)alloc((size_t)4096*256*2);
  unsigned short* cat1  = (unsigned short*)alloc((size_t)4096*384*2);
  unsigned short* atp   = (unsigned short*)alloc((size_t)4096*128*2);
  unsigned short* femb  = (unsigned short*)alloc((size_t)131072*64*2);
  float*          lpw   = (float*)         alloc((size_t)4*128*256*4);
  unsigned short* P12   = (unsigned short*)alloc((size_t)4096*512*2);
  unsigned short* P1Tp  = (unsigned short*)alloc((size_t)128*16*64*8*2);
  unsigned short* P2Tp  = (unsigned short*)alloc((size_t)128*16*64*8*2);
  unsigned short* gf    = (unsigned short*)alloc((size_t)128*256*2);
  unsigned short* t1    = (unsigned short*)alloc((size_t)4096*256*2);
  unsigned short* Wsp   = (unsigned short*)alloc((size_t)4*16*1024);
  unsigned short* Wnp   = (unsigned short*)alloc((size_t)12*16*1024);
  unsigned short* typep = (unsigned short*)alloc((size_t)8*7*1024);
  unsigned short* polarp= (unsigned short*)alloc((size_t)8*1*1024);
  unsigned short* fracp = (unsigned short*)alloc((size_t)8*1*1024);
  unsigned short* W12p  = (unsigned short*)alloc((size_t)8*32*1024);
  unsigned short* W1botp= (unsigned short*)alloc((size_t)2*16*1024);
  unsigned short* W2Tp  = (unsigned short*)alloc((size_t)8*16*1024);
  unsigned short* a1p   = (unsigned short*)alloc((size_t)16*16*1024);
  unsigned short* a2p   = (unsigned short*)alloc((size_t)8*16*1024);

  k_pack_misc<<<dim3(328), dim3(64), 0, stream>>>(Ws, Wn, typeW, polarW, fracW,
                                                  Wsp, Wnp, typep, polarp, fracp);
  k_pad <<<dim3(2048), dim3(256), 0, stream>>>(at, atp);
  k_time<<<dim3(128),  dim3(128), 0, stream>>>(t, cat1);
  // type_emb = at_pad @ Ws + bs  -> cat1[:, 0:256]
  k_gemm<<<dim3(64,4), dim3(256), 0, stream>>>(atp, 128, Wsp, 4, 16, bs,
      (float*)nullptr, 0, cat1, 384, (const float*)nullptr, 256, 2);
  // nf0 = cat1 @ Wn + bn  -> nf (f32) and cat2 left half (bf16)
  k_gemm<<<dim3(64,4), dim3(256), 0, stream>>>(cat1, 384, Wnp, 12, 16, bn,
      nf, 256, cat2, 512, (const float*)nullptr, 256, 2);
  k_femb<<<dim3(512), dim3(256), 0, stream>>>(fc, femb);
  k_lpw <<<dim3(512), dim3(256), 0, stream>>>(lpol, m1W, m1b, lpw);

  for (int l = 0; l < 4; ++l){
    k_ln<<<dim3(1024), dim3(256), 0, stream>>>(nf, ln_g + l*256, ln_b + l*256, h);
    k_pack_layer<<<dim3(800), dim3(64), 0, stream>>>(
        m1W + (size_t)l*578*256, m2W + (size_t)l*65536,
        a1W + (size_t)l*131072,  a2W + (size_t)l*65536,
        W12p, W1botp, W2Tp, a1p, a2p);
    // P12 = h @ [W1a | W1b]
    k_gemm<<<dim3(64,8), dim3(256), 0, stream>>>(h, 256, W12p, 8, 32,
        (const float*)nullptr, (float*)nullptr, 0, P12, 512,
        (const float*)nullptr, 512, 0);
    k_pack_P<<<dim3(4096), dim3(64), 0, stream>>>(P12, lpw + (size_t)l*32768, P1Tp, P2Tp);
    k_edge<<<dim3(512), dim3(512), 0, stream>>>(femb, W1botp, P1Tp, P2Tp, W2Tp,
                                                m2b + l*256, cat2);
    // a1 = silu(cat2 @ a1_W + b)
    k_gemm<<<dim3(64,4), dim3(256), 0, stream>>>(cat2, 512, a1p, 16, 16, a1b + l*256,
        (float*)nullptr, 0, t1, 256, (const float*)nullptr, 256, 3);
    // nf += silu(t1 @ a2_W + b); also refresh cat2 left half
    k_gemm<<<dim3(64,4), dim3(256), 0, stream>>>(t1, 256, a2p, 8, 16, a2b + l*256,
        nf, 256, cat2, 512, nf, 256, 7);
  }

  k_ln   <<<dim3(1024), dim3(256), 0, stream>>>(nf, flng, flnb, h);
  k_gmean<<<dim3(128),  dim3(256), 0, stream>>>(h, gf);
  // type_pred
  k_gemm<<<dim3(64,2), dim3(256), 0, stream>>>(h, 256, typep, 8, 7, typeb,
      out, 100, (unsigned short*)nullptr, 0, (const float*)nullptr, 100, 2);
  // l_polar_pred
  k_gemm<<<dim3(2,1), dim3(256), 0, stream>>>(gf, 256, polarp, 8, 1,
      (const float*)nullptr, out + 409600, 6, (unsigned short*)nullptr, 0,
      (const float*)nullptr, 6, 0);
  // frac_coords_pred
  k_gemm<<<dim3(64,1), dim3(256), 0, stream>>>(h, 256, fracp, 8, 1,
      (const float*)nullptr, out + 410368, 3, (unsigned short*)nullptr, 0,
      (const float*)nullptr, 3, 0);
}

// Round 3
// 511.759 us; speedup vs baseline: 1.3181x; 1.3181x over previous
//
#include <hip/hip_runtime.h>
#include <hip/hip_bf16.h>

// ---- types / helpers -------------------------------------------------------
typedef __attribute__((ext_vector_type(8))) short short8;
typedef __attribute__((ext_vector_type(4))) short short4v;
typedef __attribute__((ext_vector_type(4))) float float4v;
typedef __bf16 bf16x8 __attribute__((ext_vector_type(8)));

#define MFMA16(A,B,C) __builtin_amdgcn_mfma_f32_16x16x32_bf16( \
    __builtin_bit_cast(bf16x8,(A)), __builtin_bit_cast(bf16x8,(B)), (C), 0, 0, 0)

static __device__ __forceinline__ float bf2f(unsigned short b){
  unsigned u = ((unsigned)b) << 16; float f; __builtin_memcpy(&f,&u,sizeof(f)); return f;
}
static __device__ __forceinline__ unsigned short f2bf(float f){
  unsigned u; __builtin_memcpy(&u,&f,sizeof(u));
  u = (u + 0x7FFFu + ((u>>16)&1u)) >> 16; return (unsigned short)u;
}
static __device__ __forceinline__ float siluf(float x){
  return x * __builtin_amdgcn_rcpf(1.0f + __expf(-x));
}
static __device__ __forceinline__ float ldf(const float* p, size_t i){ return p[i]; }
static __device__ __forceinline__ float ldf(const unsigned short* p, size_t i){ return bf2f(p[i]); }

// ---- generic packed-B MFMA GEMM -------------------------------------------
// C[M x Nc] = op(A[M x K] @ W[K x Nc]); A row-major bf16; W pre-packed into
// 16x16x32 B-fragment tiles: Bp[(kt*NT + nt)*64 + lane][8].
// flags: 1=silu, 2=bias, 4=residual(res, stride ldoF)
__global__ __launch_bounds__(256) void k_gemm(
    const unsigned short* __restrict__ A, int lda,
    const unsigned short* __restrict__ Bp, int KT, int NT,
    const float* __restrict__ bias,
    float* __restrict__ outF, int ldoF,
    unsigned short* __restrict__ outH, int ldoH,
    const float* __restrict__ res,
    int Nc, int flags)
{
  const int w = threadIdx.x >> 6, lane = threadIdx.x & 63;
  const int l15 = lane & 15, q = lane >> 4;
  const int rowL = blockIdx.x * 64 + w * 16;   // wave's 16-row tile
  const int colB = blockIdx.y * 64;
  const short8* pa = (const short8*)(A + (size_t)(rowL + l15) * lda);
  const short8* pb = (const short8*)Bp;
  float4v acc[4] = {};
  int ntc[4];
  #pragma unroll
  for (int i = 0; i < 4; ++i){ int t = (colB >> 4) + i; ntc[i] = t < NT ? t : NT - 1; }
  for (int kt = 0; kt < KT; ++kt){
    short8 a = pa[kt * 4 + q];
    #pragma unroll
    for (int i = 0; i < 4; ++i){
      short8 b = pb[(size_t)(kt * NT + ntc[i]) * 64 + lane];
      acc[i] = MFMA16(a, b, acc[i]);
    }
  }
  const bool doB = flags & 2, doS = flags & 1, doR = flags & 4;
  #pragma unroll
  for (int i = 0; i < 4; ++i){
    int c = colB + i * 16 + l15;
    if (c >= Nc) continue;
    float bv = doB ? bias[c] : 0.0f;
    #pragma unroll
    for (int r = 0; r < 4; ++r){
      int row = rowL + q * 4 + r;
      float v = acc[i][r] + bv;
      if (doS) v = siluf(v);
      if (doR) v += res[(size_t)row * ldoF + c];
      if (outF) outF[(size_t)row * ldoF + c] = v;
      if (outH) outH[(size_t)row * ldoH + c] = f2bf(v);
    }
  }
}

// ---- weight packing into fragment order ------------------------------------
// dst tile index (kt*NTtot + ntoff + nt); value = W[kt*32 + q*8 + j][nt*16 + l15]
template<typename T>
static __device__ __forceinline__ void pack_tile(
    const T* W, int ldw, int Krows, int Ncols,
    unsigned short* dst, int NTtot, int ntoff, int kt, int nt,
    const float* addrow)
{
  int lane = threadIdx.x;
  int l15 = lane & 15, q = lane >> 4;
  int col = nt * 16 + l15;
  int kr0 = kt * 32 + q * 8;
  short8 v;
  #pragma unroll
  for (int j = 0; j < 8; ++j){
    int r = kr0 + j;
    float x = 0.0f;
    if (r < Krows && col < Ncols){
      x = ldf(W, (size_t)r * ldw + col);
      if (addrow) x += addrow[(r >> 5) * 256 + col];
    }
    v[j] = (short)f2bf(x);
  }
  ((short8*)dst)[(size_t)(kt * NTtot + ntoff + nt) * 64 + lane] = v;
}

__global__ void k_pack_misc(
    const float* Ws, const float* Wn,
    const float* typeW, const float* polarW, const float* fracW,
    unsigned short* Wsp, unsigned short* Wnp, unsigned short* typep,
    unsigned short* polarp, unsigned short* fracp)
{
  int b = blockIdx.x;
  if (b < 64)        pack_tile(Ws,    256, 100, 256, Wsp,   16, 0, b >> 4, b & 15, nullptr);
  else if (b < 256){ int s = b - 64;  pack_tile(Wn,    256, 384, 256, Wnp,   16, 0, s >> 4, s & 15, nullptr); }
  else if (b < 312){ int s = b - 256; pack_tile(typeW, 100, 256, 100, typep,  7, 0, s / 7,  s % 7,  nullptr); }
  else if (b < 320){ int s = b - 312; pack_tile(polarW,  6, 256,   6, polarp, 1, 0, s, 0, nullptr); }
  else             { int s = b - 320; pack_tile(fracW,   3, 256,   3, fracp,  1, 0, s, 0, nullptr); }
}

// all 4 layers packed in one launch; per-layer regions (element strides):
// W12p 131072, W1botp 16384, W2Tp 65536, a1p 131072, a2p 65536
__global__ void k_pack_layers(
    const float* m1W, const float* m2W,
    const float* a1W, const float* a2W,
    unsigned short* W12p, unsigned short* W1botp, unsigned short* W2Tp,
    unsigned short* a1p, unsigned short* a2p)
{
  int bb = blockIdx.x;
  int l = bb / 800, b = bb % 800;
  const float* m1Wl = m1W + (size_t)l * 578 * 256;
  const float* m2Wl = m2W + (size_t)l * 65536;
  const float* a1Wl = a1W + (size_t)l * 131072;
  const float* a2Wl = a2W + (size_t)l * 65536;
  unsigned short* W12pl   = W12p   + (size_t)l * 131072;
  unsigned short* W1botpl = W1botp + (size_t)l * 16384;
  unsigned short* W2Tpl   = W2Tp   + (size_t)l * 65536;
  unsigned short* a1pl    = a1p    + (size_t)l * 131072;
  unsigned short* a2pl    = a2p    + (size_t)l * 65536;
  if (b < 128)       pack_tile(m1Wl,           256, 256, 256, W12pl,  32,  0, b >> 4, b & 15, nullptr);
  else if (b < 256){ int s = b - 128; pack_tile(m1Wl + 256*256, 256, 256, 256, W12pl,  32, 16, s >> 4, s & 15, nullptr); }
  else if (b < 288){ int s = b - 256; pack_tile(m1Wl + 512*256, 256,  64, 256, W1botpl,16,  0, s >> 4, s & 15, nullptr); }
  else if (b < 416){ int s = b - 288; pack_tile(m2Wl,           256, 256, 256, W2Tpl,  16,  0, s >> 4, s & 15, nullptr); }
  else if (b < 672){ int s = b - 416; pack_tile(a1Wl,           256, 512, 256, a1pl,   16,  0, s >> 4, s & 15, nullptr); }
  else             { int s = b - 672; pack_tile(a2Wl,           256, 256, 256, a2pl,   16,  0, s >> 4, s & 15, nullptr); }
}

// pack P2^T (per graph, kt==graph) and P1^T (+lpw per graph) from P12[4096x512]
__global__ void k_pack_P(const unsigned short* P12, const float* lpwl,
                         unsigned short* P1Tp, unsigned short* P2Tp)
{
  int b = blockIdx.x;
  if (b < 2048)      pack_tile(P12 + 256, 512, 4096, 256, P2Tp, 16, 0, b >> 4, b & 15, nullptr);
  else { int s = b - 2048; pack_tile(P12, 512, 4096, 256, P1Tp, 16, 0, s >> 4, s & 15, lpwl); }
}

// ---- small prep kernels ----------------------------------------------------
// b<2048: pad atom_types into atp; b>=2048: time embedding into cat1
__global__ void k_prep(const float* at, const float* t,
                       unsigned short* atp, unsigned short* cat1)
{
  int b = blockIdx.x;
  if (b < 2048){
    int id = b * 256 + threadIdx.x;   // 4096*128
    int r = id >> 7, c = id & 127;
    atp[id] = (c < 100) ? f2bf(at[r * 100 + c]) : (unsigned short)0;
  } else {
    int g = b - 2048, i = threadIdx.x;
    if (i < 128){
      float tg = t[g];
      int f = i & 63;
      float fr = __expf((-9.210340371976184f / 63.0f) * (float)f);
      float arg = tg * fr;
      float v = (i < 64) ? __sinf(arg) : __cosf(arg);
      unsigned short hv = f2bf(v);
      for (int n = 0; n < 32; ++n)
        cat1[(size_t)(g * 32 + n) * 384 + 256 + i] = hv;
    }
  }
}

// b<512: femb for 256 edges; b>=512: lpw[l][g][c]
__global__ void k_femb_lpw(const float* fc, const float* lpol,
                           const float* m1W, const float* m1b,
                           unsigned short* femb, float* lpw)
{
  int b = blockIdx.x;
  if (b < 512){
    int e = b * 256 + threadIdx.x;    // E = 131072
    int g = e >> 10, i = (e >> 5) & 31, j = e & 31;
    int nt = g * 32 + i, ns = g * 32 + j;
    unsigned short o[64];
    #pragma unroll
    for (int k = 0; k < 3; ++k){
      float d = fc[ns * 3 + k] - fc[nt * 3 + k];
      d -= floorf(d);
      #pragma unroll
      for (int f = 0; f < 10; ++f){
        float ang = d * (6.283185307179586f * (float)f);
        o[k * 10 + f]      = f2bf(__sinf(ang));
        o[30 + k * 10 + f] = f2bf(__cosf(ang));
      }
    }
    #pragma unroll
    for (int z = 60; z < 64; ++z) o[z] = 0;
    short8* dst = (short8*)(femb + (size_t)e * 64);
    #pragma unroll
    for (int v = 0; v < 8; ++v){
      short8 s;
      #pragma unroll
      for (int j2 = 0; j2 < 8; ++j2) s[j2] = (short)o[v * 8 + j2];
      dst[v] = s;
    }
  } else {
    int s = b - 512;
    int l = s >> 7, g = s & 127, c = threadIdx.x;
    const float* W = m1W + (size_t)l * 578 * 256;
    float acc = m1b[l * 256 + c];
    #pragma unroll
    for (int k = 0; k < 6; ++k)
      acc += lpol[g * 6 + k] * W[(572 + k) * 256 + c];
    lpw[((size_t)l * 128 + g) * 256 + c] = acc;
  }
}

// layernorm: 4 rows/block (1 wave each), H=256
__global__ __launch_bounds__(256) void k_ln(
    const float* __restrict__ nf, const float* __restrict__ g,
    const float* __restrict__ bta, unsigned short* __restrict__ h)
{
  int w = threadIdx.x >> 6, lane = threadIdx.x & 63;
  int row = blockIdx.x * 4 + w;
  float4v x = *(const float4v*)(nf + (size_t)row * 256 + lane * 4);
  float s = x[0] + x[1] + x[2] + x[3];
  #pragma unroll
  for (int m = 1; m < 64; m <<= 1) s += __shfl_xor(s, m, 64);
  float mu = s * (1.0f / 256.0f);
  float d0 = x[0] - mu, d1 = x[1] - mu, d2 = x[2] - mu, d3 = x[3] - mu;
  float vs = d0 * d0 + d1 * d1 + d2 * d2 + d3 * d3;
  #pragma unroll
  for (int m = 1; m < 64; m <<= 1) vs += __shfl_xor(vs, m, 64);
  float rs = rsqrtf(vs * (1.0f / 256.0f) + 1e-5f);
  float4v gg = *(const float4v*)(g + lane * 4);
  float4v bb = *(const float4v*)(bta + lane * 4);
  short4v o;
  o[0] = (short)f2bf(d0 * rs * gg[0] + bb[0]);
  o[1] = (short)f2bf(d1 * rs * gg[1] + bb[1]);
  o[2] = (short)f2bf(d2 * rs * gg[2] + bb[2]);
  o[3] = (short)f2bf(d3 * rs * gg[3] + bb[3]);
  *(short4v*)(h + (size_t)row * 256 + lane * 4) = o;
}

__global__ void k_gmean(const unsigned short* h, unsigned short* gf)
{
  int g = blockIdx.x, c = threadIdx.x;
  float s = 0.0f;
  for (int n = 0; n < 32; ++n) s += bf2f(h[(size_t)(g * 32 + n) * 256 + c]);
  gf[g * 256 + c] = f2bf(s * (1.0f / 32.0f));
}

// ---- fused edge kernel -----------------------------------------------------
// block = 8 waves = 512 thr, covers 256 edges (8 target nodes) in 2 halves.
// M1^T = MFMA over K=128: [femb(64) | src-onehot(32)->P2 | node-onehot(32)->P1+lpw]
// then M2^T = M1 @ m2_W via W2^T frags, silu, mean over 32 edges -> cat2 right half.
// EST=268 shorts (134 dwords, == 6 mod 32 banks): bank-balanced b64 writes & b128 reads.
// __launch_bounds__(512,2): 128-VGPR budget (4 waves/SIMD) — fits ~110-reg working
// set without scratch spill (512,4 gave a 64-VGPR budget -> 290 MB spill traffic).
#define EST 268
__global__ __launch_bounds__(512, 2) void k_edge(
    const unsigned short* __restrict__ femb,
    const unsigned short* __restrict__ W1botp,
    const unsigned short* __restrict__ P1Tp,
    const unsigned short* __restrict__ P2Tp,
    const unsigned short* __restrict__ W2Tp,
    const float* __restrict__ b2,
    unsigned short* __restrict__ cat2)
{
  __shared__ unsigned short M1[128 * EST];   // 68.6 KB
  const int w = threadIdx.x >> 6, lane = threadIdx.x & 63;
  const int l15 = lane & 15, q = lane >> 4;
  const int b = blockIdx.x, g = b >> 2;
  const int cb = w * 32;                     // wave's 32-channel chunk
  const short8* fb8  = (const short8*)femb;
  const short8* w1b8 = (const short8*)W1botp;
  const short8* p1t8 = (const short8*)P1Tp;
  const short8* p2t8 = (const short8*)P2Tp;
  const short8* w2t8 = (const short8*)W2Tp;

  short8 ohj[2];                             // src-onehot per e-tile parity
  #pragma unroll
  for (int p = 0; p < 2; ++p){
    int tgt = p * 16 + l15;
    #pragma unroll
    for (int j = 0; j < 8; ++j) ohj[p][j] = (short)((q * 8 + j) == tgt ? 0x3F80 : 0);
  }

  for (int half = 0; half < 2; ++half){
    short8 ohn[4];                           // node-onehot per node in half
    #pragma unroll
    for (int nn = 0; nn < 4; ++nn){
      int tgt = (b & 3) * 8 + half * 4 + nn;
      #pragma unroll
      for (int j = 0; j < 8; ++j) ohn[nn][j] = (short)((q * 8 + j) == tgt ? 0x3F80 : 0);
    }
    // ---- build M1^T ----
    float4v acc[2][8] = {};
    #pragma unroll
    for (int ks = 0; ks < 4; ++ks){
      short8 a0, a1;
      if (ks < 2)      { a0 = w1b8[(size_t)(ks * 16 + w * 2 + 0) * 64 + lane];
                         a1 = w1b8[(size_t)(ks * 16 + w * 2 + 1) * 64 + lane]; }
      else if (ks == 2){ a0 = p2t8[(size_t)(g * 16 + w * 2 + 0) * 64 + lane];
                         a1 = p2t8[(size_t)(g * 16 + w * 2 + 1) * 64 + lane]; }
      else             { a0 = p1t8[(size_t)(g * 16 + w * 2 + 0) * 64 + lane];
                         a1 = p1t8[(size_t)(g * 16 + w * 2 + 1) * 64 + lane]; }
      #pragma unroll
      for (int et = 0; et < 8; ++et){
        short8 bf;
        if (ks < 2){
          int edge = b * 256 + half * 128 + et * 16 + l15;
          bf = fb8[(size_t)edge * 8 + ks * 4 + q];
        } else if (ks == 2) bf = ohj[et & 1];
        else                bf = ohn[et >> 1];
        acc[0][et] = MFMA16(a0, bf, acc[0][et]);
        acc[1][et] = MFMA16(a1, bf, acc[1][et]);
      }
    }
    // silu -> M1 LDS (row e, contiguous channels)
    #pragma unroll
    for (int ct = 0; ct < 2; ++ct)
      #pragma unroll
      for (int et = 0; et < 8; ++et){
        short4v sv;
        #pragma unroll
        for (int r = 0; r < 4; ++r) sv[r] = (short)f2bf(siluf(acc[ct][et][r]));
        *(short4v*)(&M1[(size_t)(et * 16 + l15) * EST + cb + ct * 16 + q * 4]) = sv;
      }
    __syncthreads();
    // ---- M2^T ----
    float4v c2[2][8] = {};
    #pragma unroll
    for (int kt = 0; kt < 8; ++kt){
      short8 a0 = w2t8[(size_t)(kt * 16 + w * 2 + 0) * 64 + lane];
      short8 a1 = w2t8[(size_t)(kt * 16 + w * 2 + 1) * 64 + lane];
      #pragma unroll
      for (int et = 0; et < 8; ++et){
        short8 bf = *(const short8*)(&M1[(size_t)(et * 16 + l15) * EST + kt * 32 + q * 8]);
        c2[0][et] = MFMA16(a0, bf, c2[0][et]);
        c2[1][et] = MFMA16(a1, bf, c2[1][et]);
      }
    }
    __syncthreads();
    // bias + silu + mean over 32 edges -> cat2[node][256 + c]
    float bv[2][4];
    #pragma unroll
    for (int ct = 0; ct < 2; ++ct)
      #pragma unroll
      for (int r = 0; r < 4; ++r) bv[ct][r] = b2[cb + ct * 16 + q * 4 + r];
    #pragma unroll
    for (int nn = 0; nn < 4; ++nn){
      float vv[2][4];
      #pragma unroll
      for (int ct = 0; ct < 2; ++ct)
        #pragma unroll
        for (int r = 0; r < 4; ++r){
          float v = siluf(c2[ct][2 * nn][r] + bv[ct][r])
                  + siluf(c2[ct][2 * nn + 1][r] + bv[ct][r]);
          v += __shfl_xor(v, 1, 16);
          v += __shfl_xor(v, 2, 16);
          v += __shfl_xor(v, 4, 16);
          v += __shfl_xor(v, 8, 16);
          vv[ct][r] = v;
        }
      if (l15 == 0){
        int node = b * 8 + half * 4 + nn;
        #pragma unroll
        for (int ct = 0; ct < 2; ++ct)
          #pragma unroll
          for (int r = 0; r < 4; ++r)
            cat2[(size_t)node * 512 + 256 + cb + ct * 16 + q * 4 + r] =
                f2bf(vv[ct][r] * (1.0f / 32.0f));
      }
    }
  }
}

// ---- launcher --------------------------------------------------------------
extern "C" void kernel_launch(void* const* d_in, const int* in_sizes, int n_in,
                              void* d_out, int out_size, void* d_ws, size_t ws_size,
                              hipStream_t stream)
{
  const float* t      = (const float*)d_in[0];
  const float* at     = (const float*)d_in[1];
  const float* fc     = (const float*)d_in[2];
  const float* lpol   = (const float*)d_in[3];
  const float* Ws     = (const float*)d_in[5];
  const float* bs     = (const float*)d_in[6];
  const float* Wn     = (const float*)d_in[7];
  const float* bn     = (const float*)d_in[8];
  const float* ln_g   = (const float*)d_in[9];
  const float* ln_b   = (const float*)d_in[10];
  const float* m1W    = (const float*)d_in[11];
  const float* m1b    = (const float*)d_in[12];
  const float* m2W    = (const float*)d_in[13];
  const float* m2b    = (const float*)d_in[14];
  const float* a1W    = (const float*)d_in[15];
  const float* a1b    = (const float*)d_in[16];
  const float* a2W    = (const float*)d_in[17];
  const float* a2b    = (const float*)d_in[18];
  const float* flng   = (const float*)d_in[19];
  const float* flnb   = (const float*)d_in[20];
  const float* typeW  = (const float*)d_in[21];
  const float* typeb  = (const float*)d_in[22];
  const float* polarW = (const float*)d_in[23];
  const float* fracW  = (const float*)d_in[24];
  float* out = (float*)d_out;

  char* ws = (char*)d_ws;
  size_t off = 0;
  auto alloc = [&](size_t bytes) -> char* {
    char* p = ws + off; off += (bytes + 255) & ~(size_t)255; return p;
  };
  float*          nf    = (float*)         alloc((size_t)4096*256*4);
  unsigned short* cat2  = (unsigned short*)alloc((size_t)4096*512*2);
  unsigned short* h     = (unsigned short*)alloc((size_t)4096*256*2);
  unsigned short* cat1  = (unsigned short*)alloc((size_t)4096*384*2);
  unsigned short* atp   = (unsigned short*)alloc((size_t)4096*128*2);
  unsigned short* femb  = (unsigned short*)alloc((size_t)131072*64*2);
  float*          lpw   = (float*)         alloc((size_t)4*128*256*4);
  unsigned short* P12   = (unsigned short*)alloc((size_t)4096*512*2);
  unsigned short* P1Tp  = (unsigned short*)alloc((size_t)128*16*64*8*2);
  unsigned short* P2Tp  = (unsigned short*)alloc((size_t)128*16*64*8*2);
  unsigned short* gf    = (unsigned short*)alloc((size_t)128*256*2);
  unsigned short* t1    = (unsigned short*)alloc((size_t)4096*256*2);
  unsigned short* Wsp   = (unsigned short*)alloc((size_t)4*16*1024);
  unsigned short* Wnp   = (unsigned short*)alloc((size_t)12*16*1024);
  unsigned short* typep = (unsigned short*)alloc((size_t)8*7*1024);
  unsigned short* polarp= (unsigned short*)alloc((size_t)8*1*1024);
  unsigned short* fracp = (unsigned short*)alloc((size_t)8*1*1024);
  unsigned short* W12p  = (unsigned short*)alloc((size_t)4*131072*2);
  unsigned short* W1botp= (unsigned short*)alloc((size_t)4*16384*2);
  unsigned short* W2Tp  = (unsigned short*)alloc((size_t)4*65536*2);
  unsigned short* a1p   = (unsigned short*)alloc((size_t)4*131072*2);
  unsigned short* a2p   = (unsigned short*)alloc((size_t)4*65536*2);

  k_pack_misc<<<dim3(328), dim3(64), 0, stream>>>(Ws, Wn, typeW, polarW, fracW,
                                                  Wsp, Wnp, typep, polarp, fracp);
  k_pack_layers<<<dim3(3200), dim3(64), 0, stream>>>(m1W, m2W, a1W, a2W,
                                                     W12p, W1botp, W2Tp, a1p, a2p);
  k_prep<<<dim3(2176), dim3(256), 0, stream>>>(at, t, atp, cat1);
  // type_emb = at_pad @ Ws + bs  -> cat1[:, 0:256]
  k_gemm<<<dim3(64,4), dim3(256), 0, stream>>>(atp, 128, Wsp, 4, 16, bs,
      (float*)nullptr, 0, cat1, 384, (const float*)nullptr, 256, 2);
  // nf0 = cat1 @ Wn + bn  -> nf (f32) and cat2 left half (bf16)
  k_gemm<<<dim3(64,4), dim3(256), 0, stream>>>(cat1, 384, Wnp, 12, 16, bn,
      nf, 256, cat2, 512, (const float*)nullptr, 256, 2);
  k_femb_lpw<<<dim3(1024), dim3(256), 0, stream>>>(fc, lpol, m1W, m1b, femb, lpw);

  for (int l = 0; l < 4; ++l){
    k_ln<<<dim3(1024), dim3(256), 0, stream>>>(nf, ln_g + l*256, ln_b + l*256, h);
    // P12 = h @ [W1a | W1b]
    k_gemm<<<dim3(64,8), dim3(256), 0, stream>>>(h, 256, W12p + (size_t)l*131072, 8, 32,
        (const float*)nullptr, (float*)nullptr, 0, P12, 512,
        (const float*)nullptr, 512, 0);
    k_pack_P<<<dim3(4096), dim3(64), 0, stream>>>(P12, lpw + (size_t)l*32768, P1Tp, P2Tp);
    k_edge<<<dim3(512), dim3(512), 0, stream>>>(femb, W1botp + (size_t)l*16384,
                                                P1Tp, P2Tp, W2Tp + (size_t)l*65536,
                                                m2b + l*256, cat2);
    // a1 = silu(cat2 @ a1_W + b)
    k_gemm<<<dim3(64,4), dim3(256), 0, stream>>>(cat2, 512, a1p + (size_t)l*131072, 16, 16,
        a1b + l*256, (float*)nullptr, 0, t1, 256, (const float*)nullptr, 256, 3);
    // nf += silu(t1 @ a2_W + b); also refresh cat2 left half
    k_gemm<<<dim3(64,4), dim3(256), 0, stream>>>(t1, 256, a2p + (size_t)l*65536, 8, 16,
        a2b + l*256, nf, 256, cat2, 512, nf, 256, 7);
  }

  k_ln   <<<dim3(1024), dim3(256), 0, stream>>>(nf, flng, flnb, h);
  k_gmean<<<dim3(128),  dim3(256), 0, stream>>>(h, gf);
  // type_pred
  k_gemm<<<dim3(64,2), dim3(256), 0, stream>>>(h, 256, typep, 8, 7, typeb,
      out, 100, (unsigned short*)nullptr, 0, (const float*)nullptr, 100, 2);
  // l_polar_pred
  k_gemm<<<dim3(2,1), dim3(256), 0, stream>>>(gf, 256, polarp, 8, 1,
      (const float*)nullptr, out + 409600, 6, (unsigned short*)nullptr, 0,
      (const float*)nullptr, 6, 0);
  // frac_coords_pred
  k_gemm<<<dim3(64,1), dim3(256), 0, stream>>>(h, 256, fracp, 8, 1,
      (const float*)nullptr, out + 410368, 3, (unsigned short*)nullptr, 0,
      (const float*)nullptr, 3, 0);
}

// Round 4
// 494.582 us; speedup vs baseline: 1.3639x; 1.0347x over previous
//
#include <hip/hip_runtime.h>
#include <hip/hip_bf16.h>

// ---- types / helpers -------------------------------------------------------
typedef __attribute__((ext_vector_type(8))) short short8;
typedef __attribute__((ext_vector_type(4))) short short4v;
typedef __attribute__((ext_vector_type(4))) float float4v;
typedef __bf16 bf16x8 __attribute__((ext_vector_type(8)));

#define MFMA16(A,B,C) __builtin_amdgcn_mfma_f32_16x16x32_bf16( \
    __builtin_bit_cast(bf16x8,(A)), __builtin_bit_cast(bf16x8,(B)), (C), 0, 0, 0)

static __device__ __forceinline__ float bf2f(unsigned short b){
  unsigned u = ((unsigned)b) << 16; float f; __builtin_memcpy(&f,&u,sizeof(f)); return f;
}
static __device__ __forceinline__ unsigned short f2bf(float f){
  unsigned u; __builtin_memcpy(&u,&f,sizeof(u));
  u = (u + 0x7FFFu + ((u>>16)&1u)) >> 16; return (unsigned short)u;
}
static __device__ __forceinline__ float siluf(float x){
  return x * __builtin_amdgcn_rcpf(1.0f + __expf(-x));
}
static __device__ __forceinline__ float ldf(const float* p, size_t i){ return p[i]; }
static __device__ __forceinline__ float ldf(const unsigned short* p, size_t i){ return bf2f(p[i]); }

// ---- generic packed-B MFMA GEMM -------------------------------------------
// flags: 1=silu, 2=bias, 4=residual(res, stride ldoF)
__global__ __launch_bounds__(256) void k_gemm(
    const unsigned short* __restrict__ A, int lda,
    const unsigned short* __restrict__ Bp, int KT, int NT,
    const float* __restrict__ bias,
    float* __restrict__ outF, int ldoF,
    unsigned short* __restrict__ outH, int ldoH,
    const float* __restrict__ res,
    int Nc, int flags)
{
  const int w = threadIdx.x >> 6, lane = threadIdx.x & 63;
  const int l15 = lane & 15, q = lane >> 4;
  const int rowL = blockIdx.x * 64 + w * 16;
  const int colB = blockIdx.y * 64;
  const short8* pa = (const short8*)(A + (size_t)(rowL + l15) * lda);
  const short8* pb = (const short8*)Bp;
  float4v acc[4] = {};
  int ntc[4];
  #pragma unroll
  for (int i = 0; i < 4; ++i){ int t = (colB >> 4) + i; ntc[i] = t < NT ? t : NT - 1; }
  for (int kt = 0; kt < KT; ++kt){
    short8 a = pa[kt * 4 + q];
    #pragma unroll
    for (int i = 0; i < 4; ++i){
      short8 b = pb[(size_t)(kt * NT + ntc[i]) * 64 + lane];
      acc[i] = MFMA16(a, b, acc[i]);
    }
  }
  const bool doB = flags & 2, doS = flags & 1, doR = flags & 4;
  #pragma unroll
  for (int i = 0; i < 4; ++i){
    int c = colB + i * 16 + l15;
    if (c >= Nc) continue;
    float bv = doB ? bias[c] : 0.0f;
    #pragma unroll
    for (int r = 0; r < 4; ++r){
      int row = rowL + q * 4 + r;
      float v = acc[i][r] + bv;
      if (doS) v = siluf(v);
      if (doR) v += res[(size_t)row * ldoF + c];
      if (outF) outF[(size_t)row * ldoF + c] = v;
      if (outH) outH[(size_t)row * ldoH + c] = f2bf(v);
    }
  }
}

// ---- weight packing into fragment order ------------------------------------
// dst tile index (kt*NTtot + ntoff + nt); value = W[kt*32 + q*8 + j][nt*16 + l15]
template<typename T>
static __device__ __forceinline__ void pack_tile(
    const T* W, int ldw, int Krows, int Ncols,
    unsigned short* dst, int NTtot, int ntoff, int kt, int nt,
    const float* addrow)
{
  int lane = threadIdx.x;
  int l15 = lane & 15, q = lane >> 4;
  int col = nt * 16 + l15;
  int kr0 = kt * 32 + q * 8;
  short8 v;
  #pragma unroll
  for (int j = 0; j < 8; ++j){
    int r = kr0 + j;
    float x = 0.0f;
    if (r < Krows && col < Ncols){
      x = ldf(W, (size_t)r * ldw + col);
      if (addrow) x += addrow[(r >> 5) * 256 + col];
    }
    v[j] = (short)f2bf(x);
  }
  ((short8*)dst)[(size_t)(kt * NTtot + ntoff + nt) * 64 + lane] = v;
}

// all weight packing in one launch (64-thread blocks)
__global__ void k_packW(
    const float* Ws, const float* Wn,
    const float* typeW, const float* polarW, const float* fracW,
    const float* m1W, const float* m2W, const float* a1W, const float* a2W,
    unsigned short* Wsp, unsigned short* Wnp, unsigned short* typep,
    unsigned short* polarp, unsigned short* fracp,
    unsigned short* W12p, unsigned short* W1botp, unsigned short* W2Tp,
    unsigned short* a1p, unsigned short* a2p)
{
  int b = blockIdx.x;
  if (b < 64)      { pack_tile(Ws,    256, 100, 256, Wsp,   16, 0, b >> 4, b & 15, nullptr); return; }
  if (b < 256){ int s = b - 64;  pack_tile(Wn,    256, 384, 256, Wnp,   16, 0, s >> 4, s & 15, nullptr); return; }
  if (b < 312){ int s = b - 256; pack_tile(typeW, 100, 256, 100, typep,  7, 0, s / 7,  s % 7,  nullptr); return; }
  if (b < 320){ int s = b - 312; pack_tile(polarW,  6, 256,   6, polarp, 1, 0, s, 0, nullptr); return; }
  if (b < 328){ int s = b - 320; pack_tile(fracW,   3, 256,   3, fracp,  1, 0, s, 0, nullptr); return; }
  int s2 = b - 328;                   // 3200 layer-pack blocks
  int l = s2 / 800, bb = s2 % 800;
  const float* m1Wl = m1W + (size_t)l * 578 * 256;
  const float* m2Wl = m2W + (size_t)l * 65536;
  const float* a1Wl = a1W + (size_t)l * 131072;
  const float* a2Wl = a2W + (size_t)l * 65536;
  unsigned short* W12pl   = W12p   + (size_t)l * 131072;
  unsigned short* W1botpl = W1botp + (size_t)l * 16384;
  unsigned short* W2Tpl   = W2Tp   + (size_t)l * 65536;
  unsigned short* a1pl    = a1p    + (size_t)l * 131072;
  unsigned short* a2pl    = a2p    + (size_t)l * 65536;
  if (bb < 128)       pack_tile(m1Wl,           256, 256, 256, W12pl,  32,  0, bb >> 4, bb & 15, nullptr);
  else if (bb < 256){ int s = bb - 128; pack_tile(m1Wl + 256*256, 256, 256, 256, W12pl,  32, 16, s >> 4, s & 15, nullptr); }
  else if (bb < 288){ int s = bb - 256; pack_tile(m1Wl + 512*256, 256,  64, 256, W1botpl,16,  0, s >> 4, s & 15, nullptr); }
  else if (bb < 416){ int s = bb - 288; pack_tile(m2Wl,           256, 256, 256, W2Tpl,  16,  0, s >> 4, s & 15, nullptr); }
  else if (bb < 672){ int s = bb - 416; pack_tile(a1Wl,           256, 512, 256, a1pl,   16,  0, s >> 4, s & 15, nullptr); }
  else              { int s = bb - 672; pack_tile(a2Wl,           256, 256, 256, a2pl,   16,  0, s >> 4, s & 15, nullptr); }
}

// ---- all activation preprocessing in one launch (256-thread blocks) --------
// b<2048: pad atom_types; b<2176: time emb; b<2688: femb; else lpw
__global__ void k_prep2(const float* at, const float* t, const float* fc,
                        const float* lpol, const float* m1W, const float* m1b,
                        unsigned short* atp, unsigned short* cat1,
                        unsigned short* femb, float* lpw)
{
  int b = blockIdx.x;
  if (b < 2048){
    int id = b * 256 + threadIdx.x;
    int r = id >> 7, c = id & 127;
    atp[id] = (c < 100) ? f2bf(at[r * 100 + c]) : (unsigned short)0;
  } else if (b < 2176){
    int g = b - 2048, i = threadIdx.x;
    if (i < 128){
      float tg = t[g];
      int f = i & 63;
      float fr = __expf((-9.210340371976184f / 63.0f) * (float)f);
      float arg = tg * fr;
      float v = (i < 64) ? __sinf(arg) : __cosf(arg);
      unsigned short hv = f2bf(v);
      for (int n = 0; n < 32; ++n)
        cat1[(size_t)(g * 32 + n) * 384 + 256 + i] = hv;
    }
  } else if (b < 2688){
    int e = (b - 2176) * 256 + threadIdx.x;    // E = 131072
    int g = e >> 10, i = (e >> 5) & 31, j = e & 31;
    int nt = g * 32 + i, ns = g * 32 + j;
    unsigned short o[64];
    #pragma unroll
    for (int k = 0; k < 3; ++k){
      float d = fc[ns * 3 + k] - fc[nt * 3 + k];
      d -= floorf(d);
      #pragma unroll
      for (int f = 0; f < 10; ++f){
        float ang = d * (6.283185307179586f * (float)f);
        o[k * 10 + f]      = f2bf(__sinf(ang));
        o[30 + k * 10 + f] = f2bf(__cosf(ang));
      }
    }
    #pragma unroll
    for (int z = 60; z < 64; ++z) o[z] = 0;
    short8* dst = (short8*)(femb + (size_t)e * 64);
    #pragma unroll
    for (int v = 0; v < 8; ++v){
      short8 s;
      #pragma unroll
      for (int j2 = 0; j2 < 8; ++j2) s[j2] = (short)o[v * 8 + j2];
      dst[v] = s;
    }
  } else {
    int s = b - 2688;
    int l = s >> 7, g = s & 127, c = threadIdx.x;
    const float* W = m1W + (size_t)l * 578 * 256;
    float acc = m1b[l * 256 + c];
    #pragma unroll
    for (int k = 0; k < 6; ++k)
      acc += lpol[g * 6 + k] * W[(572 + k) * 256 + c];
    lpw[((size_t)l * 128 + g) * 256 + c] = acc;
  }
}

#define HLD 264   // LDS row stride (shorts) for 256-col bf16 tiles; 528B = 33*16

// ---- fused LN + P12 GEMM + fragment-pack -----------------------------------
// one block per graph (128 blocks, 256 thr). LN(nf[g])->h_lds; P=h@[W1a|W1b]
// (+lpw on P1); transpose via LDS; write P1Tp/P2Tp in MFMA-A-fragment order.
__global__ __launch_bounds__(256) void k_lnP(
    const float* __restrict__ nf, const float* __restrict__ g_,
    const float* __restrict__ b_,
    const unsigned short* __restrict__ W12p, const float* __restrict__ lpwl,
    unsigned short* __restrict__ P1Tp, unsigned short* __restrict__ P2Tp)
{
  __shared__ unsigned short hld[32 * HLD];   // 16.9 KB
  __shared__ unsigned short PT[512 * 40];    // 40 KB  (PT[ch][node], stride 40)
  const int w = threadIdx.x >> 6, lane = threadIdx.x & 63;
  const int l15 = lane & 15, q = lane >> 4;
  const int g = blockIdx.x;
  // LN: wave w -> rows w*8..w*8+7
  #pragma unroll
  for (int rr = 0; rr < 8; ++rr){
    int row = w * 8 + rr;
    float4v x = *(const float4v*)(nf + ((size_t)(g*32+row))*256 + lane*4);
    float s = x[0]+x[1]+x[2]+x[3];
    #pragma unroll
    for (int m=1;m<64;m<<=1) s += __shfl_xor(s,m,64);
    float mu = s * (1.f/256.f);
    float d0=x[0]-mu,d1=x[1]-mu,d2=x[2]-mu,d3=x[3]-mu;
    float vs=d0*d0+d1*d1+d2*d2+d3*d3;
    #pragma unroll
    for (int m=1;m<64;m<<=1) vs += __shfl_xor(vs,m,64);
    float rs = rsqrtf(vs*(1.f/256.f)+1e-5f);
    float4v gg = *(const float4v*)(g_ + lane*4);
    float4v bb = *(const float4v*)(b_ + lane*4);
    short4v o;
    o[0]=(short)f2bf(d0*rs*gg[0]+bb[0]);
    o[1]=(short)f2bf(d1*rs*gg[1]+bb[1]);
    o[2]=(short)f2bf(d2*rs*gg[2]+bb[2]);
    o[3]=(short)f2bf(d3*rs*gg[3]+bb[3]);
    *(short4v*)(&hld[row*HLD + lane*4]) = o;
  }
  __syncthreads();
  // GEMM 32x512, K=256; wave w -> nt w*8..w*8+7 of 32
  float4v acc[2][8] = {};
  const short8* pb = (const short8*)W12p;
  for (int kt = 0; kt < 8; ++kt){
    short8 a0 = *(const short8*)(&hld[(size_t)l15*HLD + kt*32 + q*8]);
    short8 a1 = *(const short8*)(&hld[(size_t)(16+l15)*HLD + kt*32 + q*8]);
    #pragma unroll
    for (int i = 0; i < 8; ++i){
      short8 bfr = pb[(size_t)(kt*32 + w*8 + i)*64 + lane];
      acc[0][i] = MFMA16(a0, bfr, acc[0][i]);
      acc[1][i] = MFMA16(a1, bfr, acc[1][i]);
    }
  }
  // +lpw on P1 cols (tiles<16), bf16 -> PT[ch][node]
  #pragma unroll
  for (int i = 0; i < 8; ++i){
    int T = w*8 + i;
    float lv = (T < 16) ? lpwl[g*256 + T*16 + l15] : 0.0f;
    #pragma unroll
    for (int mt = 0; mt < 2; ++mt){
      short4v o;
      #pragma unroll
      for (int r = 0; r < 4; ++r) o[r] = (short)f2bf(acc[mt][i][r] + lv);
      *(short4v*)(&PT[(size_t)(T*16 + l15)*40 + mt*16 + q*4]) = o;
    }
  }
  __syncthreads();
  // packed write: frag elem j = P[node=q*8+j][ch=T*16+l15] = PT[ch][q*8+j]
  #pragma unroll
  for (int s = 0; s < 8; ++s){
    int T = w + s*4;
    short8 v = *(const short8*)(&PT[(size_t)(T*16 + l15)*40 + q*8]);
    unsigned short* dst = (T < 16) ? (P1Tp + ((size_t)(g*16 + T)*64 + lane)*8)
                                   : (P2Tp + ((size_t)(g*16 + (T-16))*64 + lane)*8);
    *(short8*)dst = v;
  }
}

// ---- fused a1+a2 epilogue MLP ----------------------------------------------
// block = 32 node rows (128 blocks, 256 thr). t1 = silu(cat2@a1W+b) in LDS;
// nf += silu(t1@a2W+b); refresh cat2 left half.
__global__ __launch_bounds__(256) void k_a12(
    const unsigned short* __restrict__ cat2,
    const unsigned short* __restrict__ a1pl, const float* __restrict__ a1bl,
    const unsigned short* __restrict__ a2pl, const float* __restrict__ a2bl,
    float* __restrict__ nf, unsigned short* __restrict__ cat2w)
{
  __shared__ unsigned short t1[32 * HLD];   // 16.9 KB
  const int w = threadIdx.x >> 6, lane = threadIdx.x & 63;
  const int l15 = lane & 15, q = lane >> 4;
  const int r0 = blockIdx.x * 32;
  const short8* pb1 = (const short8*)a1pl;
  const short8* pb2 = (const short8*)a2pl;
  float4v acc[2][4] = {};
  for (int kt = 0; kt < 16; ++kt){
    short8 a0 = *(const short8*)(cat2 + (size_t)(r0 + l15)*512 + kt*32 + q*8);
    short8 a1 = *(const short8*)(cat2 + (size_t)(r0 + 16 + l15)*512 + kt*32 + q*8);
    #pragma unroll
    for (int i = 0; i < 4; ++i){
      short8 bfr = pb1[(size_t)(kt*16 + w*4 + i)*64 + lane];
      acc[0][i] = MFMA16(a0, bfr, acc[0][i]);
      acc[1][i] = MFMA16(a1, bfr, acc[1][i]);
    }
  }
  #pragma unroll
  for (int i = 0; i < 4; ++i){
    int c = (w*4+i)*16 + l15;
    float bv = a1bl[c];
    #pragma unroll
    for (int mt = 0; mt < 2; ++mt)
      #pragma unroll
      for (int r = 0; r < 4; ++r)
        t1[(size_t)(mt*16 + q*4 + r)*HLD + c] = f2bf(siluf(acc[mt][i][r] + bv));
  }
  __syncthreads();
  float4v c2[2][4] = {};
  for (int kt = 0; kt < 8; ++kt){
    short8 a0 = *(const short8*)(&t1[(size_t)l15*HLD + kt*32 + q*8]);
    short8 a1 = *(const short8*)(&t1[(size_t)(16 + l15)*HLD + kt*32 + q*8]);
    #pragma unroll
    for (int i = 0; i < 4; ++i){
      short8 bfr = pb2[(size_t)(kt*16 + w*4 + i)*64 + lane];
      c2[0][i] = MFMA16(a0, bfr, c2[0][i]);
      c2[1][i] = MFMA16(a1, bfr, c2[1][i]);
    }
  }
  #pragma unroll
  for (int i = 0; i < 4; ++i){
    int c = (w*4+i)*16 + l15;
    float bv = a2bl[c];
    #pragma unroll
    for (int mt = 0; mt < 2; ++mt)
      #pragma unroll
      for (int r = 0; r < 4; ++r){
        int row = r0 + mt*16 + q*4 + r;
        float v = nf[(size_t)row*256 + c] + siluf(c2[mt][i][r] + bv);
        nf[(size_t)row*256 + c] = v;
        cat2w[(size_t)row*512 + c] = f2bf(v);
      }
  }
}

// ---- final LN + graph mean --------------------------------------------------
__global__ __launch_bounds__(256) void k_lnF(
    const float* __restrict__ nf, const float* __restrict__ g_,
    const float* __restrict__ b_,
    unsigned short* __restrict__ h, unsigned short* __restrict__ gf)
{
  __shared__ unsigned short hld[32 * HLD];
  const int w = threadIdx.x >> 6, lane = threadIdx.x & 63;
  const int g = blockIdx.x;
  #pragma unroll
  for (int rr = 0; rr < 8; ++rr){
    int row = w * 8 + rr;
    float4v x = *(const float4v*)(nf + ((size_t)(g*32+row))*256 + lane*4);
    float s = x[0]+x[1]+x[2]+x[3];
    #pragma unroll
    for (int m=1;m<64;m<<=1) s += __shfl_xor(s,m,64);
    float mu = s * (1.f/256.f);
    float d0=x[0]-mu,d1=x[1]-mu,d2=x[2]-mu,d3=x[3]-mu;
    float vs=d0*d0+d1*d1+d2*d2+d3*d3;
    #pragma unroll
    for (int m=1;m<64;m<<=1) vs += __shfl_xor(vs,m,64);
    float rs = rsqrtf(vs*(1.f/256.f)+1e-5f);
    float4v gg = *(const float4v*)(g_ + lane*4);
    float4v bb = *(const float4v*)(b_ + lane*4);
    short4v o;
    o[0]=(short)f2bf(d0*rs*gg[0]+bb[0]);
    o[1]=(short)f2bf(d1*rs*gg[1]+bb[1]);
    o[2]=(short)f2bf(d2*rs*gg[2]+bb[2]);
    o[3]=(short)f2bf(d3*rs*gg[3]+bb[3]);
    *(short4v*)(&hld[row*HLD + lane*4]) = o;
    *(short4v*)(h + ((size_t)(g*32+row))*256 + lane*4) = o;
  }
  __syncthreads();
  int c = threadIdx.x;
  float s = 0.0f;
  #pragma unroll
  for (int n = 0; n < 32; ++n) s += bf2f(hld[n*HLD + c]);
  gf[g*256 + c] = f2bf(s * (1.0f/32.0f));
}

// ---- fused edge kernel (unchanged structure; bias hoisted) ------------------
#define EST 268
__global__ __launch_bounds__(512, 2) void k_edge(
    const unsigned short* __restrict__ femb,
    const unsigned short* __restrict__ W1botp,
    const unsigned short* __restrict__ P1Tp,
    const unsigned short* __restrict__ P2Tp,
    const unsigned short* __restrict__ W2Tp,
    const float* __restrict__ b2,
    unsigned short* __restrict__ cat2)
{
  __shared__ unsigned short M1[128 * EST];   // 68.6 KB
  const int w = threadIdx.x >> 6, lane = threadIdx.x & 63;
  const int l15 = lane & 15, q = lane >> 4;
  const int b = blockIdx.x, g = b >> 2;
  const int cb = w * 32;
  const short8* fb8  = (const short8*)femb;
  const short8* w1b8 = (const short8*)W1botp;
  const short8* p1t8 = (const short8*)P1Tp;
  const short8* p2t8 = (const short8*)P2Tp;
  const short8* w2t8 = (const short8*)W2Tp;

  short8 ohj[2];
  #pragma unroll
  for (int p = 0; p < 2; ++p){
    int tgt = p * 16 + l15;
    #pragma unroll
    for (int j = 0; j < 8; ++j) ohj[p][j] = (short)((q * 8 + j) == tgt ? 0x3F80 : 0);
  }
  float bv[2][4];
  #pragma unroll
  for (int ct = 0; ct < 2; ++ct)
    #pragma unroll
    for (int r = 0; r < 4; ++r) bv[ct][r] = b2[cb + ct * 16 + q * 4 + r];

  for (int half = 0; half < 2; ++half){
    short8 ohn[4];
    #pragma unroll
    for (int nn = 0; nn < 4; ++nn){
      int tgt = (b & 3) * 8 + half * 4 + nn;
      #pragma unroll
      for (int j = 0; j < 8; ++j) ohn[nn][j] = (short)((q * 8 + j) == tgt ? 0x3F80 : 0);
    }
    float4v acc[2][8] = {};
    #pragma unroll
    for (int ks = 0; ks < 4; ++ks){
      short8 a0, a1;
      if (ks < 2)      { a0 = w1b8[(size_t)(ks * 16 + w * 2 + 0) * 64 + lane];
                         a1 = w1b8[(size_t)(ks * 16 + w * 2 + 1) * 64 + lane]; }
      else if (ks == 2){ a0 = p2t8[(size_t)(g * 16 + w * 2 + 0) * 64 + lane];
                         a1 = p2t8[(size_t)(g * 16 + w * 2 + 1) * 64 + lane]; }
      else             { a0 = p1t8[(size_t)(g * 16 + w * 2 + 0) * 64 + lane];
                         a1 = p1t8[(size_t)(g * 16 + w * 2 + 1) * 64 + lane]; }
      #pragma unroll
      for (int et = 0; et < 8; ++et){
        short8 bf;
        if (ks < 2){
          int edge = b * 256 + half * 128 + et * 16 + l15;
          bf = fb8[(size_t)edge * 8 + ks * 4 + q];
        } else if (ks == 2) bf = ohj[et & 1];
        else                bf = ohn[et >> 1];
        acc[0][et] = MFMA16(a0, bf, acc[0][et]);
        acc[1][et] = MFMA16(a1, bf, acc[1][et]);
      }
    }
    #pragma unroll
    for (int ct = 0; ct < 2; ++ct)
      #pragma unroll
      for (int et = 0; et < 8; ++et){
        short4v sv;
        #pragma unroll
        for (int r = 0; r < 4; ++r) sv[r] = (short)f2bf(siluf(acc[ct][et][r]));
        *(short4v*)(&M1[(size_t)(et * 16 + l15) * EST + cb + ct * 16 + q * 4]) = sv;
      }
    __syncthreads();
    float4v c2[2][8] = {};
    #pragma unroll
    for (int kt = 0; kt < 8; ++kt){
      short8 a0 = w2t8[(size_t)(kt * 16 + w * 2 + 0) * 64 + lane];
      short8 a1 = w2t8[(size_t)(kt * 16 + w * 2 + 1) * 64 + lane];
      #pragma unroll
      for (int et = 0; et < 8; ++et){
        short8 bf = *(const short8*)(&M1[(size_t)(et * 16 + l15) * EST + kt * 32 + q * 8]);
        c2[0][et] = MFMA16(a0, bf, c2[0][et]);
        c2[1][et] = MFMA16(a1, bf, c2[1][et]);
      }
    }
    __syncthreads();
    #pragma unroll
    for (int nn = 0; nn < 4; ++nn){
      float vv[2][4];
      #pragma unroll
      for (int ct = 0; ct < 2; ++ct)
        #pragma unroll
        for (int r = 0; r < 4; ++r){
          float v = siluf(c2[ct][2 * nn][r] + bv[ct][r])
                  + siluf(c2[ct][2 * nn + 1][r] + bv[ct][r]);
          v += __shfl_xor(v, 1, 16);
          v += __shfl_xor(v, 2, 16);
          v += __shfl_xor(v, 4, 16);
          v += __shfl_xor(v, 8, 16);
          vv[ct][r] = v;
        }
      if (l15 == 0){
        int node = b * 8 + half * 4 + nn;
        #pragma unroll
        for (int ct = 0; ct < 2; ++ct)
          #pragma unroll
          for (int r = 0; r < 4; ++r)
            cat2[(size_t)node * 512 + 256 + cb + ct * 16 + q * 4 + r] =
                f2bf(vv[ct][r] * (1.0f / 32.0f));
      }
    }
  }
}

// ---- launcher --------------------------------------------------------------
extern "C" void kernel_launch(void* const* d_in, const int* in_sizes, int n_in,
                              void* d_out, int out_size, void* d_ws, size_t ws_size,
                              hipStream_t stream)
{
  const float* t      = (const float*)d_in[0];
  const float* at     = (const float*)d_in[1];
  const float* fc     = (const float*)d_in[2];
  const float* lpol   = (const float*)d_in[3];
  const float* Ws     = (const float*)d_in[5];
  const float* bs     = (const float*)d_in[6];
  const float* Wn     = (const float*)d_in[7];
  const float* bn     = (const float*)d_in[8];
  const float* ln_g   = (const float*)d_in[9];
  const float* ln_b   = (const float*)d_in[10];
  const float* m1W    = (const float*)d_in[11];
  const float* m1b    = (const float*)d_in[12];
  const float* m2W    = (const float*)d_in[13];
  const float* m2b    = (const float*)d_in[14];
  const float* a1W    = (const float*)d_in[15];
  const float* a1b    = (const float*)d_in[16];
  const float* a2W    = (const float*)d_in[17];
  const float* a2b    = (const float*)d_in[18];
  const float* flng   = (const float*)d_in[19];
  const float* flnb   = (const float*)d_in[20];
  const float* typeW  = (const float*)d_in[21];
  const float* typeb  = (const float*)d_in[22];
  const float* polarW = (const float*)d_in[23];
  const float* fracW  = (const float*)d_in[24];
  float* out = (float*)d_out;

  char* ws = (char*)d_ws;
  size_t off = 0;
  auto alloc = [&](size_t bytes) -> char* {
    char* p = ws + off; off += (bytes + 255) & ~(size_t)255; return p;
  };
  float*          nf    = (float*)         alloc((size_t)4096*256*4);
  unsigned short* cat2  = (unsigned short*)alloc((size_t)4096*512*2);
  unsigned short* h     = (unsigned short*)alloc((size_t)4096*256*2);
  unsigned short* cat1  = (unsigned short*)alloc((size_t)4096*384*2);
  unsigned short* atp   = (unsigned short*)alloc((size_t)4096*128*2);
  unsigned short* femb  = (unsigned short*)alloc((size_t)131072*64*2);
  float*          lpw   = (float*)         alloc((size_t)4*128*256*4);
  unsigned short* P1Tp  = (unsigned short*)alloc((size_t)128*16*64*8*2);
  unsigned short* P2Tp  = (unsigned short*)alloc((size_t)128*16*64*8*2);
  unsigned short* gf    = (unsigned short*)alloc((size_t)128*256*2);
  unsigned short* Wsp   = (unsigned short*)alloc((size_t)4*16*1024);
  unsigned short* Wnp   = (unsigned short*)alloc((size_t)12*16*1024);
  unsigned short* typep = (unsigned short*)alloc((size_t)8*7*1024);
  unsigned short* polarp= (unsigned short*)alloc((size_t)8*1*1024);
  unsigned short* fracp = (unsigned short*)alloc((size_t)8*1*1024);
  unsigned short* W12p  = (unsigned short*)alloc((size_t)4*131072*2);
  unsigned short* W1botp= (unsigned short*)alloc((size_t)4*16384*2);
  unsigned short* W2Tp  = (unsigned short*)alloc((size_t)4*65536*2);
  unsigned short* a1p   = (unsigned short*)alloc((size_t)4*131072*2);
  unsigned short* a2p   = (unsigned short*)alloc((size_t)4*65536*2);

  k_packW<<<dim3(3528), dim3(64), 0, stream>>>(Ws, Wn, typeW, polarW, fracW,
      m1W, m2W, a1W, a2W,
      Wsp, Wnp, typep, polarp, fracp, W12p, W1botp, W2Tp, a1p, a2p);
  k_prep2<<<dim3(3200), dim3(256), 0, stream>>>(at, t, fc, lpol, m1W, m1b,
                                                atp, cat1, femb, lpw);
  // type_emb = at_pad @ Ws + bs  -> cat1[:, 0:256]
  k_gemm<<<dim3(64,4), dim3(256), 0, stream>>>(atp, 128, Wsp, 4, 16, bs,
      (float*)nullptr, 0, cat1, 384, (const float*)nullptr, 256, 2);
  // nf0 = cat1 @ Wn + bn  -> nf (f32) and cat2 left half (bf16)
  k_gemm<<<dim3(64,4), dim3(256), 0, stream>>>(cat1, 384, Wnp, 12, 16, bn,
      nf, 256, cat2, 512, (const float*)nullptr, 256, 2);

  for (int l = 0; l < 4; ++l){
    k_lnP<<<dim3(128), dim3(256), 0, stream>>>(nf, ln_g + l*256, ln_b + l*256,
        W12p + (size_t)l*131072, lpw + (size_t)l*32768, P1Tp, P2Tp);
    k_edge<<<dim3(512), dim3(512), 0, stream>>>(femb, W1botp + (size_t)l*16384,
        P1Tp, P2Tp, W2Tp + (size_t)l*65536, m2b + l*256, cat2);
    k_a12<<<dim3(128), dim3(256), 0, stream>>>(cat2, a1p + (size_t)l*131072,
        a1b + l*256, a2p + (size_t)l*65536, a2b + l*256, nf, cat2);
  }

  k_lnF<<<dim3(128), dim3(256), 0, stream>>>(nf, flng, flnb, h, gf);
  // type_pred
  k_gemm<<<dim3(64,2), dim3(256), 0, stream>>>(h, 256, typep, 8, 7, typeb,
      out, 100, (unsigned short*)nullptr, 0, (const float*)nullptr, 100, 2);
  // l_polar_pred
  k_gemm<<<dim3(2,1), dim3(256), 0, stream>>>(gf, 256, polarp, 8, 1,
      (const float*)nullptr, out + 409600, 6, (unsigned short*)nullptr, 0,
      (const float*)nullptr, 6, 0);
  // frac_coords_pred
  k_gemm<<<dim3(64,1), dim3(256), 0, stream>>>(h, 256, fracp, 8, 1,
      (const float*)nullptr, out + 410368, 3, (unsigned short*)nullptr, 0,
      (const float*)nullptr, 3, 0);
}

// Round 5
// 396.638 us; speedup vs baseline: 1.7007x; 1.2469x over previous
//
#include <hip/hip_runtime.h>
#include <hip/hip_bf16.h>

// ---- types / helpers -------------------------------------------------------
typedef __attribute__((ext_vector_type(8))) short short8;
typedef __attribute__((ext_vector_type(4))) short short4v;
typedef __attribute__((ext_vector_type(4))) float float4v;
typedef __bf16 bf16x8 __attribute__((ext_vector_type(8)));

#define MFMA16(A,B,C) __builtin_amdgcn_mfma_f32_16x16x32_bf16( \
    __builtin_bit_cast(bf16x8,(A)), __builtin_bit_cast(bf16x8,(B)), (C), 0, 0, 0)

static __device__ __forceinline__ float bf2f(unsigned short b){
  unsigned u = ((unsigned)b) << 16; float f; __builtin_memcpy(&f,&u,sizeof(f)); return f;
}
static __device__ __forceinline__ unsigned short f2bf(float f){
  unsigned u; __builtin_memcpy(&u,&f,sizeof(u));
  u = (u + 0x7FFFu + ((u>>16)&1u)) >> 16; return (unsigned short)u;
}
static __device__ __forceinline__ float siluf(float x){
  return x * __builtin_amdgcn_rcpf(1.0f + __expf(-x));
}
static __device__ __forceinline__ float ldf(const float* p, size_t i){ return p[i]; }
static __device__ __forceinline__ float ldf(const unsigned short* p, size_t i){ return bf2f(p[i]); }

// ---- generic packed-B MFMA GEMM -------------------------------------------
// flags: 1=silu, 2=bias, 4=residual(res, stride ldoF)
__global__ __launch_bounds__(256) void k_gemm(
    const unsigned short* __restrict__ A, int lda,
    const unsigned short* __restrict__ Bp, int KT, int NT,
    const float* __restrict__ bias,
    float* __restrict__ outF, int ldoF,
    unsigned short* __restrict__ outH, int ldoH,
    const float* __restrict__ res,
    int Nc, int flags)
{
  const int w = threadIdx.x >> 6, lane = threadIdx.x & 63;
  const int l15 = lane & 15, q = lane >> 4;
  const int rowL = blockIdx.x * 64 + w * 16;
  const int colB = blockIdx.y * 64;
  const short8* pa = (const short8*)(A + (size_t)(rowL + l15) * lda);
  const short8* pb = (const short8*)Bp;
  float4v acc[4] = {};
  int ntc[4];
  #pragma unroll
  for (int i = 0; i < 4; ++i){ int t = (colB >> 4) + i; ntc[i] = t < NT ? t : NT - 1; }
  for (int kt = 0; kt < KT; ++kt){
    short8 a = pa[kt * 4 + q];
    #pragma unroll
    for (int i = 0; i < 4; ++i){
      short8 b = pb[(size_t)(kt * NT + ntc[i]) * 64 + lane];
      acc[i] = MFMA16(a, b, acc[i]);
    }
  }
  const bool doB = flags & 2, doS = flags & 1, doR = flags & 4;
  #pragma unroll
  for (int i = 0; i < 4; ++i){
    int c = colB + i * 16 + l15;
    if (c >= Nc) continue;
    float bv = doB ? bias[c] : 0.0f;
    #pragma unroll
    for (int r = 0; r < 4; ++r){
      int row = rowL + q * 4 + r;
      float v = acc[i][r] + bv;
      if (doS) v = siluf(v);
      if (doR) v += res[(size_t)row * ldoF + c];
      if (outF) outF[(size_t)row * ldoF + c] = v;
      if (outH) outH[(size_t)row * ldoH + c] = f2bf(v);
    }
  }
}

// ---- weight packing into fragment order ------------------------------------
// dst tile index (kt*NTtot + ntoff + nt); value = W[kt*32 + q*8 + j][nt*16 + l15]
template<typename T>
static __device__ __forceinline__ void pack_tile(
    const T* W, int ldw, int Krows, int Ncols,
    unsigned short* dst, int NTtot, int ntoff, int kt, int nt,
    const float* addrow)
{
  int lane = threadIdx.x;
  int l15 = lane & 15, q = lane >> 4;
  int col = nt * 16 + l15;
  int kr0 = kt * 32 + q * 8;
  short8 v;
  #pragma unroll
  for (int j = 0; j < 8; ++j){
    int r = kr0 + j;
    float x = 0.0f;
    if (r < Krows && col < Ncols){
      x = ldf(W, (size_t)r * ldw + col);
      if (addrow) x += addrow[(r >> 5) * 256 + col];
    }
    v[j] = (short)f2bf(x);
  }
  ((short8*)dst)[(size_t)(kt * NTtot + ntoff + nt) * 64 + lane] = v;
}

// all weight packing in one launch (64-thread blocks)
__global__ void k_packW(
    const float* Ws, const float* Wn,
    const float* typeW, const float* polarW, const float* fracW,
    const float* m1W, const float* m2W, const float* a1W, const float* a2W,
    unsigned short* Wsp, unsigned short* Wnp, unsigned short* typep,
    unsigned short* polarp, unsigned short* fracp,
    unsigned short* W12p, unsigned short* W1botp, unsigned short* W2Tp,
    unsigned short* a1p, unsigned short* a2p)
{
  int b = blockIdx.x;
  if (b < 64)      { pack_tile(Ws,    256, 100, 256, Wsp,   16, 0, b >> 4, b & 15, nullptr); return; }
  if (b < 256){ int s = b - 64;  pack_tile(Wn,    256, 384, 256, Wnp,   16, 0, s >> 4, s & 15, nullptr); return; }
  if (b < 312){ int s = b - 256; pack_tile(typeW, 100, 256, 100, typep,  7, 0, s / 7,  s % 7,  nullptr); return; }
  if (b < 320){ int s = b - 312; pack_tile(polarW,  6, 256,   6, polarp, 1, 0, s, 0, nullptr); return; }
  if (b < 328){ int s = b - 320; pack_tile(fracW,   3, 256,   3, fracp,  1, 0, s, 0, nullptr); return; }
  int s2 = b - 328;                   // 3200 layer-pack blocks
  int l = s2 / 800, bb = s2 % 800;
  const float* m1Wl = m1W + (size_t)l * 578 * 256;
  const float* m2Wl = m2W + (size_t)l * 65536;
  const float* a1Wl = a1W + (size_t)l * 131072;
  const float* a2Wl = a2W + (size_t)l * 65536;
  unsigned short* W12pl   = W12p   + (size_t)l * 131072;
  unsigned short* W1botpl = W1botp + (size_t)l * 16384;
  unsigned short* W2Tpl   = W2Tp   + (size_t)l * 65536;
  unsigned short* a1pl    = a1p    + (size_t)l * 131072;
  unsigned short* a2pl    = a2p    + (size_t)l * 65536;
  if (bb < 128)       pack_tile(m1Wl,           256, 256, 256, W12pl,  32,  0, bb >> 4, bb & 15, nullptr);
  else if (bb < 256){ int s = bb - 128; pack_tile(m1Wl + 256*256, 256, 256, 256, W12pl,  32, 16, s >> 4, s & 15, nullptr); }
  else if (bb < 288){ int s = bb - 256; pack_tile(m1Wl + 512*256, 256,  64, 256, W1botpl,16,  0, s >> 4, s & 15, nullptr); }
  else if (bb < 416){ int s = bb - 288; pack_tile(m2Wl,           256, 256, 256, W2Tpl,  16,  0, s >> 4, s & 15, nullptr); }
  else if (bb < 672){ int s = bb - 416; pack_tile(a1Wl,           256, 512, 256, a1pl,   16,  0, s >> 4, s & 15, nullptr); }
  else              { int s = bb - 672; pack_tile(a2Wl,           256, 256, 256, a2pl,   16,  0, s >> 4, s & 15, nullptr); }
}

// ---- all activation preprocessing in one launch (256-thread blocks) --------
// b<2048: pad atom_types; b<2176: time emb; b<2688: femb; else lpw
__global__ void k_prep2(const float* at, const float* t, const float* fc,
                        const float* lpol, const float* m1W, const float* m1b,
                        unsigned short* atp, unsigned short* cat1,
                        unsigned short* femb, float* lpw)
{
  int b = blockIdx.x;
  if (b < 2048){
    int id = b * 256 + threadIdx.x;
    int r = id >> 7, c = id & 127;
    atp[id] = (c < 100) ? f2bf(at[r * 100 + c]) : (unsigned short)0;
  } else if (b < 2176){
    int g = b - 2048, i = threadIdx.x;
    if (i < 128){
      float tg = t[g];
      int f = i & 63;
      float fr = __expf((-9.210340371976184f / 63.0f) * (float)f);
      float arg = tg * fr;
      float v = (i < 64) ? __sinf(arg) : __cosf(arg);
      unsigned short hv = f2bf(v);
      for (int n = 0; n < 32; ++n)
        cat1[(size_t)(g * 32 + n) * 384 + 256 + i] = hv;
    }
  } else if (b < 2688){
    int e = (b - 2176) * 256 + threadIdx.x;    // E = 131072
    int g = e >> 10, i = (e >> 5) & 31, j = e & 31;
    int nt = g * 32 + i, ns = g * 32 + j;
    unsigned short o[64];
    #pragma unroll
    for (int k = 0; k < 3; ++k){
      float d = fc[ns * 3 + k] - fc[nt * 3 + k];
      d -= floorf(d);
      #pragma unroll
      for (int f = 0; f < 10; ++f){
        float ang = d * (6.283185307179586f * (float)f);
        o[k * 10 + f]      = f2bf(__sinf(ang));
        o[30 + k * 10 + f] = f2bf(__cosf(ang));
      }
    }
    #pragma unroll
    for (int z = 60; z < 64; ++z) o[z] = 0;
    short8* dst = (short8*)(femb + (size_t)e * 64);
    #pragma unroll
    for (int v = 0; v < 8; ++v){
      short8 s;
      #pragma unroll
      for (int j2 = 0; j2 < 8; ++j2) s[j2] = (short)o[v * 8 + j2];
      dst[v] = s;
    }
  } else {
    int s = b - 2688;
    int l = s >> 7, g = s & 127, c = threadIdx.x;
    const float* W = m1W + (size_t)l * 578 * 256;
    float acc = m1b[l * 256 + c];
    #pragma unroll
    for (int k = 0; k < 6; ++k)
      acc += lpol[g * 6 + k] * W[(572 + k) * 256 + c];
    lpw[((size_t)l * 128 + g) * 256 + c] = acc;
  }
}

#define HLD 264   // LDS row stride (shorts) for 256-col bf16 tiles

// ---- fused LN + P12 GEMM + fragment-pack -----------------------------------
// 256 blocks: (graph g, output half halfT). LN(nf[g]) -> hld (redundant x2);
// P-half = h @ W1[:, halfT*256 : +256] (+lpw on half 0); transpose via LDS;
// write P1Tp (half 0) or P2Tp (half 1) in MFMA-A-fragment order.
__global__ __launch_bounds__(256) void k_lnP(
    const float* __restrict__ nf, const float* __restrict__ g_,
    const float* __restrict__ b_,
    const unsigned short* __restrict__ W12p, const float* __restrict__ lpwl,
    unsigned short* __restrict__ P1Tp, unsigned short* __restrict__ P2Tp)
{
  __shared__ unsigned short hld[32 * HLD];   // 16.9 KB
  __shared__ unsigned short PT[256 * 40];    // 20 KB  (PT[ch][node], stride 40)
  const int w = threadIdx.x >> 6, lane = threadIdx.x & 63;
  const int l15 = lane & 15, q = lane >> 4;
  const int g = blockIdx.x >> 1, halfT = blockIdx.x & 1;
  // LN: wave w -> rows w*8..w*8+7
  #pragma unroll
  for (int rr = 0; rr < 8; ++rr){
    int row = w * 8 + rr;
    float4v x = *(const float4v*)(nf + ((size_t)(g*32+row))*256 + lane*4);
    float s = x[0]+x[1]+x[2]+x[3];
    #pragma unroll
    for (int m=1;m<64;m<<=1) s += __shfl_xor(s,m,64);
    float mu = s * (1.f/256.f);
    float d0=x[0]-mu,d1=x[1]-mu,d2=x[2]-mu,d3=x[3]-mu;
    float vs=d0*d0+d1*d1+d2*d2+d3*d3;
    #pragma unroll
    for (int m=1;m<64;m<<=1) vs += __shfl_xor(vs,m,64);
    float rs = rsqrtf(vs*(1.f/256.f)+1e-5f);
    float4v gg = *(const float4v*)(g_ + lane*4);
    float4v bb = *(const float4v*)(b_ + lane*4);
    short4v o;
    o[0]=(short)f2bf(d0*rs*gg[0]+bb[0]);
    o[1]=(short)f2bf(d1*rs*gg[1]+bb[1]);
    o[2]=(short)f2bf(d2*rs*gg[2]+bb[2]);
    o[3]=(short)f2bf(d3*rs*gg[3]+bb[3]);
    *(short4v*)(&hld[row*HLD + lane*4]) = o;
  }
  __syncthreads();
  // GEMM 32x256 (K=256); wave w -> local tiles Tl = w*4..w*4+3
  float4v acc[2][4] = {};
  const short8* pb = (const short8*)W12p;
  for (int kt = 0; kt < 8; ++kt){
    short8 a0 = *(const short8*)(&hld[(size_t)l15*HLD + kt*32 + q*8]);
    short8 a1 = *(const short8*)(&hld[(size_t)(16+l15)*HLD + kt*32 + q*8]);
    #pragma unroll
    for (int i = 0; i < 4; ++i){
      short8 bfr = pb[(size_t)(kt*32 + halfT*16 + w*4 + i)*64 + lane];
      acc[0][i] = MFMA16(a0, bfr, acc[0][i]);
      acc[1][i] = MFMA16(a1, bfr, acc[1][i]);
    }
  }
  // (+lpw on half 0), bf16 -> PT[ch][node]
  #pragma unroll
  for (int i = 0; i < 4; ++i){
    int Tl = w*4 + i;
    float lv = (halfT == 0) ? lpwl[g*256 + Tl*16 + l15] : 0.0f;
    #pragma unroll
    for (int mt = 0; mt < 2; ++mt){
      short4v o;
      #pragma unroll
      for (int r = 0; r < 4; ++r) o[r] = (short)f2bf(acc[mt][i][r] + lv);
      *(short4v*)(&PT[(size_t)(Tl*16 + l15)*40 + mt*16 + q*4]) = o;
    }
  }
  __syncthreads();
  // packed write: frag elem j = P[node=q*8+j][ch=Tl*16+l15] = PT[ch][q*8+j]
  unsigned short* dstbase = halfT ? P2Tp : P1Tp;
  #pragma unroll
  for (int s = 0; s < 4; ++s){
    int Tl = w + s*4;
    short8 v = *(const short8*)(&PT[(size_t)(Tl*16 + l15)*40 + q*8]);
    *(short8*)(dstbase + ((size_t)(g*16 + Tl)*64 + lane)*8) = v;
  }
}

// ---- fused a1+a2 epilogue MLP ----------------------------------------------
// 256 blocks x 16 node rows. t1 = silu(cat2@a1W+b) in LDS;
// nf += silu(t1@a2W+b); refresh cat2 left half.
__global__ __launch_bounds__(256) void k_a12(
    const unsigned short* __restrict__ cat2,
    const unsigned short* __restrict__ a1pl, const float* __restrict__ a1bl,
    const unsigned short* __restrict__ a2pl, const float* __restrict__ a2bl,
    float* __restrict__ nf, unsigned short* __restrict__ cat2w)
{
  __shared__ unsigned short t1[16 * HLD];   // 8.4 KB
  const int w = threadIdx.x >> 6, lane = threadIdx.x & 63;
  const int l15 = lane & 15, q = lane >> 4;
  const int r0 = blockIdx.x * 16;
  const short8* pb1 = (const short8*)a1pl;
  const short8* pb2 = (const short8*)a2pl;
  float4v acc[4] = {};
  for (int kt = 0; kt < 16; ++kt){
    short8 a0 = *(const short8*)(cat2 + (size_t)(r0 + l15)*512 + kt*32 + q*8);
    #pragma unroll
    for (int i = 0; i < 4; ++i){
      short8 bfr = pb1[(size_t)(kt*16 + w*4 + i)*64 + lane];
      acc[i] = MFMA16(a0, bfr, acc[i]);
    }
  }
  #pragma unroll
  for (int i = 0; i < 4; ++i){
    int c = (w*4+i)*16 + l15;
    float bv = a1bl[c];
    #pragma unroll
    for (int r = 0; r < 4; ++r)
      t1[(size_t)(q*4 + r)*HLD + c] = f2bf(siluf(acc[i][r] + bv));
  }
  __syncthreads();
  float4v c2[4] = {};
  for (int kt = 0; kt < 8; ++kt){
    short8 a0 = *(const short8*)(&t1[(size_t)l15*HLD + kt*32 + q*8]);
    #pragma unroll
    for (int i = 0; i < 4; ++i){
      short8 bfr = pb2[(size_t)(kt*16 + w*4 + i)*64 + lane];
      c2[i] = MFMA16(a0, bfr, c2[i]);
    }
  }
  #pragma unroll
  for (int i = 0; i < 4; ++i){
    int c = (w*4+i)*16 + l15;
    float bv = a2bl[c];
    #pragma unroll
    for (int r = 0; r < 4; ++r){
      int row = r0 + q*4 + r;
      float v = nf[(size_t)row*256 + c] + siluf(c2[i][r] + bv);
      nf[(size_t)row*256 + c] = v;
      cat2w[(size_t)row*512 + c] = f2bf(v);
    }
  }
}

// ---- final LN + graph mean --------------------------------------------------
__global__ __launch_bounds__(256) void k_lnF(
    const float* __restrict__ nf, const float* __restrict__ g_,
    const float* __restrict__ b_,
    unsigned short* __restrict__ h, unsigned short* __restrict__ gf)
{
  __shared__ unsigned short hld[32 * HLD];
  const int w = threadIdx.x >> 6, lane = threadIdx.x & 63;
  const int g = blockIdx.x;
  #pragma unroll
  for (int rr = 0; rr < 8; ++rr){
    int row = w * 8 + rr;
    float4v x = *(const float4v*)(nf + ((size_t)(g*32+row))*256 + lane*4);
    float s = x[0]+x[1]+x[2]+x[3];
    #pragma unroll
    for (int m=1;m<64;m<<=1) s += __shfl_xor(s,m,64);
    float mu = s * (1.f/256.f);
    float d0=x[0]-mu,d1=x[1]-mu,d2=x[2]-mu,d3=x[3]-mu;
    float vs=d0*d0+d1*d1+d2*d2+d3*d3;
    #pragma unroll
    for (int m=1;m<64;m<<=1) vs += __shfl_xor(vs,m,64);
    float rs = rsqrtf(vs*(1.f/256.f)+1e-5f);
    float4v gg = *(const float4v*)(g_ + lane*4);
    float4v bb = *(const float4v*)(b_ + lane*4);
    short4v o;
    o[0]=(short)f2bf(d0*rs*gg[0]+bb[0]);
    o[1]=(short)f2bf(d1*rs*gg[1]+bb[1]);
    o[2]=(short)f2bf(d2*rs*gg[2]+bb[2]);
    o[3]=(short)f2bf(d3*rs*gg[3]+bb[3]);
    *(short4v*)(&hld[row*HLD + lane*4]) = o;
    *(short4v*)(h + ((size_t)(g*32+row))*256 + lane*4) = o;
  }
  __syncthreads();
  int c = threadIdx.x;
  float s = 0.0f;
  #pragma unroll
  for (int n = 0; n < 32; ++n) s += bf2f(hld[n*HLD + c]);
  gf[g*256 + c] = f2bf(s * (1.0f/32.0f));
}

// ---- fused edge kernel v3 ---------------------------------------------------
// 2048 blocks x 4 waves; block covers 64 edges (2 target nodes), ONE barrier.
// LDS 34.3 KB -> 4 blocks/CU; __launch_bounds__(256,4) -> 128-VGPR budget.
// M1^T = MFMA over K=128: [femb(64) | src-onehot(32)->P2 | node-onehot(32)->P1+lpw]
// then M2^T = silu(M1) @ m2_W, silu, mean over 32 edges -> cat2 right half.
#define EST 268
__global__ __launch_bounds__(256, 4) void k_edge(
    const unsigned short* __restrict__ femb,
    const unsigned short* __restrict__ W1botp,
    const unsigned short* __restrict__ P1Tp,
    const unsigned short* __restrict__ P2Tp,
    const unsigned short* __restrict__ W2Tp,
    const float* __restrict__ b2,
    unsigned short* __restrict__ cat2)
{
  __shared__ unsigned short M1[64 * EST];   // 34.3 KB
  const int w = threadIdx.x >> 6, lane = threadIdx.x & 63;
  const int l15 = lane & 15, q = lane >> 4;
  const int b = blockIdx.x, g = b >> 4;
  const int n0 = (b & 15) * 2;              // first of 2 local target nodes
  const int cb = w * 64;                    // wave's 64-channel chunk (4 ct tiles)
  const short8* fb8  = (const short8*)femb;
  const short8* w1b8 = (const short8*)W1botp;
  const short8* p1t8 = (const short8*)P1Tp;
  const short8* p2t8 = (const short8*)P2Tp;
  const short8* w2t8 = (const short8*)W2Tp;

  short8 ohj[2], ohn[2];
  #pragma unroll
  for (int p = 0; p < 2; ++p){
    int tj = p * 16 + l15;                  // src-onehot: j = (local_e)&31
    int tn = n0 + p;                        // node-onehot: i = n0 + (et>>1)
    #pragma unroll
    for (int j = 0; j < 8; ++j){
      ohj[p][j] = (short)((q * 8 + j) == tj ? 0x3F80 : 0);
      ohn[p][j] = (short)((q * 8 + j) == tn ? 0x3F80 : 0);
    }
  }

  // ---- phase 1: M1^T[ch][e] ----
  float4v acc[4][4] = {};
  #pragma unroll
  for (int ks = 0; ks < 4; ++ks){
    short8 a[4];
    #pragma unroll
    for (int ct = 0; ct < 4; ++ct){
      int nt = w * 4 + ct;
      if (ks < 2)       a[ct] = w1b8[(size_t)(ks * 16 + nt) * 64 + lane];
      else if (ks == 2) a[ct] = p2t8[(size_t)(g * 16 + nt) * 64 + lane];
      else              a[ct] = p1t8[(size_t)(g * 16 + nt) * 64 + lane];
    }
    #pragma unroll
    for (int et = 0; et < 4; ++et){
      short8 bf;
      if (ks < 2){
        int edge = b * 64 + et * 16 + l15;
        bf = fb8[(size_t)edge * 8 + ks * 4 + q];
      } else if (ks == 2) bf = ohj[et & 1];
      else                bf = ohn[et >> 1];
      #pragma unroll
      for (int ct = 0; ct < 4; ++ct)
        acc[ct][et] = MFMA16(a[ct], bf, acc[ct][et]);
    }
  }
  // silu -> M1 LDS (row e, contiguous channels)
  #pragma unroll
  for (int ct = 0; ct < 4; ++ct)
    #pragma unroll
    for (int et = 0; et < 4; ++et){
      short4v sv;
      #pragma unroll
      for (int r = 0; r < 4; ++r) sv[r] = (short)f2bf(siluf(acc[ct][et][r]));
      *(short4v*)(&M1[(size_t)(et * 16 + l15) * EST + cb + ct * 16 + q * 4]) = sv;
    }
  __syncthreads();
  // ---- phase 2: M2^T ----
  float4v c2[4][4] = {};
  for (int kt = 0; kt < 8; ++kt){
    short8 a[4];
    #pragma unroll
    for (int ct = 0; ct < 4; ++ct)
      a[ct] = w2t8[(size_t)(kt * 16 + w * 4 + ct) * 64 + lane];
    #pragma unroll
    for (int et = 0; et < 4; ++et){
      short8 bf = *(const short8*)(&M1[(size_t)(et * 16 + l15) * EST + kt * 32 + q * 8]);
      #pragma unroll
      for (int ct = 0; ct < 4; ++ct)
        c2[ct][et] = MFMA16(a[ct], bf, c2[ct][et]);
    }
  }
  // bias + silu + mean over 32 edges per node -> cat2[node][256 + c]
  float bv[4][4];
  #pragma unroll
  for (int ct = 0; ct < 4; ++ct)
    #pragma unroll
    for (int r = 0; r < 4; ++r) bv[ct][r] = b2[cb + ct * 16 + q * 4 + r];
  #pragma unroll
  for (int nn = 0; nn < 2; ++nn){
    #pragma unroll
    for (int ct = 0; ct < 4; ++ct){
      #pragma unroll
      for (int r = 0; r < 4; ++r){
        float v = siluf(c2[ct][2*nn][r] + bv[ct][r])
                + siluf(c2[ct][2*nn+1][r] + bv[ct][r]);
        v += __shfl_xor(v, 1, 16);
        v += __shfl_xor(v, 2, 16);
        v += __shfl_xor(v, 4, 16);
        v += __shfl_xor(v, 8, 16);
        if (l15 == 0)
          cat2[(size_t)(b*2 + nn) * 512 + 256 + cb + ct * 16 + q * 4 + r] =
              f2bf(v * (1.0f / 32.0f));
      }
    }
  }
}

// ---- launcher --------------------------------------------------------------
extern "C" void kernel_launch(void* const* d_in, const int* in_sizes, int n_in,
                              void* d_out, int out_size, void* d_ws, size_t ws_size,
                              hipStream_t stream)
{
  const float* t      = (const float*)d_in[0];
  const float* at     = (const float*)d_in[1];
  const float* fc     = (const float*)d_in[2];
  const float* lpol   = (const float*)d_in[3];
  const float* Ws     = (const float*)d_in[5];
  const float* bs     = (const float*)d_in[6];
  const float* Wn     = (const float*)d_in[7];
  const float* bn     = (const float*)d_in[8];
  const float* ln_g   = (const float*)d_in[9];
  const float* ln_b   = (const float*)d_in[10];
  const float* m1W    = (const float*)d_in[11];
  const float* m1b    = (const float*)d_in[12];
  const float* m2W    = (const float*)d_in[13];
  const float* m2b    = (const float*)d_in[14];
  const float* a1W    = (const float*)d_in[15];
  const float* a1b    = (const float*)d_in[16];
  const float* a2W    = (const float*)d_in[17];
  const float* a2b    = (const float*)d_in[18];
  const float* flng   = (const float*)d_in[19];
  const float* flnb   = (const float*)d_in[20];
  const float* typeW  = (const float*)d_in[21];
  const float* typeb  = (const float*)d_in[22];
  const float* polarW = (const float*)d_in[23];
  const float* fracW  = (const float*)d_in[24];
  float* out = (float*)d_out;

  char* ws = (char*)d_ws;
  size_t off = 0;
  auto alloc = [&](size_t bytes) -> char* {
    char* p = ws + off; off += (bytes + 255) & ~(size_t)255; return p;
  };
  float*          nf    = (float*)         alloc((size_t)4096*256*4);
  unsigned short* cat2  = (unsigned short*)alloc((size_t)4096*512*2);
  unsigned short* h     = (unsigned short*)alloc((size_t)4096*256*2);
  unsigned short* cat1  = (unsigned short*)alloc((size_t)4096*384*2);
  unsigned short* atp   = (unsigned short*)alloc((size_t)4096*128*2);
  unsigned short* femb  = (unsigned short*)alloc((size_t)131072*64*2);
  float*          lpw   = (float*)         alloc((size_t)4*128*256*4);
  unsigned short* P1Tp  = (unsigned short*)alloc((size_t)128*16*64*8*2);
  unsigned short* P2Tp  = (unsigned short*)alloc((size_t)128*16*64*8*2);
  unsigned short* gf    = (unsigned short*)alloc((size_t)128*256*2);
  unsigned short* Wsp   = (unsigned short*)alloc((size_t)4*16*1024);
  unsigned short* Wnp   = (unsigned short*)alloc((size_t)12*16*1024);
  unsigned short* typep = (unsigned short*)alloc((size_t)8*7*1024);
  unsigned short* polarp= (unsigned short*)alloc((size_t)8*1*1024);
  unsigned short* fracp = (unsigned short*)alloc((size_t)8*1*1024);
  unsigned short* W12p  = (unsigned short*)alloc((size_t)4*131072*2);
  unsigned short* W1botp= (unsigned short*)alloc((size_t)4*16384*2);
  unsigned short* W2Tp  = (unsigned short*)alloc((size_t)4*65536*2);
  unsigned short* a1p   = (unsigned short*)alloc((size_t)4*131072*2);
  unsigned short* a2p   = (unsigned short*)alloc((size_t)4*65536*2);

  k_packW<<<dim3(3528), dim3(64), 0, stream>>>(Ws, Wn, typeW, polarW, fracW,
      m1W, m2W, a1W, a2W,
      Wsp, Wnp, typep, polarp, fracp, W12p, W1botp, W2Tp, a1p, a2p);
  k_prep2<<<dim3(3200), dim3(256), 0, stream>>>(at, t, fc, lpol, m1W, m1b,
                                                atp, cat1, femb, lpw);
  // type_emb = at_pad @ Ws + bs  -> cat1[:, 0:256]
  k_gemm<<<dim3(64,4), dim3(256), 0, stream>>>(atp, 128, Wsp, 4, 16, bs,
      (float*)nullptr, 0, cat1, 384, (const float*)nullptr, 256, 2);
  // nf0 = cat1 @ Wn + bn  -> nf (f32) and cat2 left half (bf16)
  k_gemm<<<dim3(64,4), dim3(256), 0, stream>>>(cat1, 384, Wnp, 12, 16, bn,
      nf, 256, cat2, 512, (const float*)nullptr, 256, 2);

  for (int l = 0; l < 4; ++l){
    k_lnP<<<dim3(256), dim3(256), 0, stream>>>(nf, ln_g + l*256, ln_b + l*256,
        W12p + (size_t)l*131072, lpw + (size_t)l*32768, P1Tp, P2Tp);
    k_edge<<<dim3(2048), dim3(256), 0, stream>>>(femb, W1botp + (size_t)l*16384,
        P1Tp, P2Tp, W2Tp + (size_t)l*65536, m2b + l*256, cat2);
    k_a12<<<dim3(256), dim3(256), 0, stream>>>(cat2, a1p + (size_t)l*131072,
        a1b + l*256, a2p + (size_t)l*65536, a2b + l*256, nf, cat2);
  }

  k_lnF<<<dim3(128), dim3(256), 0, stream>>>(nf, flng, flnb, h, gf);
  // type_pred
  k_gemm<<<dim3(64,2), dim3(256), 0, stream>>>(h, 256, typep, 8, 7, typeb,
      out, 100, (unsigned short*)nullptr, 0, (const float*)nullptr, 100, 2);
  // l_polar_pred
  k_gemm<<<dim3(2,1), dim3(256), 0, stream>>>(gf, 256, polarp, 8, 1,
      (const float*)nullptr, out + 409600, 6, (unsigned short*)nullptr, 0,
      (const float*)nullptr, 6, 0);
  // frac_coords_pred
  k_gemm<<<dim3(64,1), dim3(256), 0, stream>>>(h, 256, fracp, 8, 1,
      (const float*)nullptr, out + 410368, 3, (unsigned short*)nullptr, 0,
      (const float*)nullptr, 3, 0);
}